// Round 9
// baseline (1890.244 us; speedup 1.0000x reference)
//
#include <hip/hip_runtime.h>
#include <math.h>

#define BB 4
#define CC 128
#define NN 4096
#define HH 64
#define WW 64
#define YTP 4356   // 66*66 padded pixel count
#define METAMAX 65536

typedef __attribute__((ext_vector_type(8))) short bf16x8;
typedef __attribute__((ext_vector_type(4))) float f32x4;

__device__ inline unsigned short f2bf(float f) {
  unsigned int u = __float_as_uint(f);
  unsigned int r = (u + 0x7FFFu + ((u >> 16) & 1u)) >> 16;
  return (unsigned short)r;
}
__device__ inline float bf2f(short s) {
  union { unsigned u; float f; } x;
  x.u = ((unsigned)(unsigned short)s) << 16;
  return x.f;
}

// ---------------- xt: transpose x -> xtb bf16 [b][n][c] ----------------
__global__ __launch_bounds__(256) void xt_kernel(
    const float* __restrict__ x, unsigned short* __restrict__ xtb) {
  int b = blockIdx.y;
  int n0 = blockIdx.x * 64;
  int t = threadIdx.x;
  __shared__ float xs[CC][65];
  for (int l = 0; l < 32; l++) {
    int idx = t + 256 * l;
    int px = idx & 63, c = idx >> 6;
    xs[c][px] = x[((size_t)b * CC + c) * NN + n0 + px];
  }
  __syncthreads();
  int n = t & 63, ch = t >> 6;
  unsigned o[16];
#pragma unroll
  for (int i = 0; i < 32; i += 2) {
    o[i >> 1] = (unsigned)f2bf(xs[32 * ch + i][n]) |
                ((unsigned)f2bf(xs[32 * ch + i + 1][n]) << 16);
  }
  unsigned short* dst = xtb + ((size_t)b * NN + n0 + n) * CC + 32 * ch;
#pragma unroll
  for (int k = 0; k < 4; k++) {
    uint4 v; v.x = o[4 * k]; v.y = o[4 * k + 1]; v.z = o[4 * k + 2]; v.w = o[4 * k + 3];
    *(uint4*)(dst + 8 * k) = v;
  }
}

// ---------------- wrepack: all weights -> bf16 packed ----------------
__global__ __launch_bounds__(256) void wrepack_kernel(
    const float* __restrict__ qw, const float* __restrict__ vw,
    const float* __restrict__ lw1w, const float* __restrict__ bw1w,
    const float* __restrict__ lw, unsigned short* __restrict__ qwb,
    unsigned short* __restrict__ vwb, unsigned short* __restrict__ hwb,
    unsigned short* __restrict__ Wt) {
  int idx = blockIdx.x * 256 + threadIdx.x;
  if (idx < 16384) { qwb[idx] = f2bf(qw[idx]); return; }
  idx -= 16384;
  if (idx < 16384) { vwb[idx] = f2bf(vw[idx]); return; }
  idx -= 16384;
  if (idx < 4096) { hwb[idx] = f2bf(lw1w[idx]); return; }
  idx -= 4096;
  if (idx < 4096) { hwb[4096 + idx] = f2bf(bw1w[idx]); return; }
  idx -= 4096;
  if (idx < CC * 1152) {
    int co = idx / 1152, rem = idx % 1152;
    int tap = rem >> 7, ci = rem & 127;
    Wt[idx] = f2bf(lw[(size_t)(co * CC + ci) * 9 + tap]);
  }
}

// ------- qv_mfma: q[n][c] + v[c][n] + nrm + qt/qtn + partial Skey/SumV + heads
__global__ __launch_bounds__(256) void qv_mfma(
    const unsigned short* __restrict__ xtb, const unsigned short* __restrict__ qwb,
    const unsigned short* __restrict__ vwb, const unsigned short* __restrict__ hwb,
    const float* __restrict__ qb, const float* __restrict__ vb,
    const float* __restrict__ lw1b, const float* __restrict__ lw2w,
    const float* __restrict__ lw2b, const float* __restrict__ bw1b,
    const float* __restrict__ bw2w, const float* __restrict__ bw2b,
    unsigned short* __restrict__ qt, unsigned short* __restrict__ qtn,
    float* __restrict__ nrm, float* __restrict__ pSkey,
    unsigned short* __restrict__ vbuf, float* __restrict__ pSumV,
    float* __restrict__ wmap, float* __restrict__ bmap) {
  int b = blockIdx.y;
  int nb = blockIdx.x;
  int n0 = nb * 64;
  int t = threadIdx.x, w = t >> 6, lane = t & 63;
  int col = lane & 15, oct = lane >> 4;
  __shared__ float qs[4][16][132];
  __shared__ float partK[4][128];
  __shared__ float partV[4][128];
  const unsigned short* xb = xtb + (size_t)b * NN * CC;

  f32x4 aq[8], av[8];
#pragma unroll
  for (int i = 0; i < 8; i++) { aq[i] = (f32x4)0.f; av[i] = (f32x4)0.f; }
#pragma unroll
  for (int kc = 0; kc < 4; kc++) {
    bf16x8 Xf = *(const bf16x8*)(xb + (size_t)(n0 + 16 * w + col) * CC + kc * 32 + oct * 8);
#pragma unroll
    for (int ct = 0; ct < 8; ct++) {
      bf16x8 Qf = *(const bf16x8*)(qwb + (16 * ct + col) * CC + kc * 32 + oct * 8);
      aq[ct] = __builtin_amdgcn_mfma_f32_16x16x32_bf16(Xf, Qf, aq[ct], 0, 0, 0);
      bf16x8 Vf = *(const bf16x8*)(vwb + (16 * ct + col) * CC + kc * 32 + oct * 8);
      av[ct] = __builtin_amdgcn_mfma_f32_16x16x32_bf16(Vf, Xf, av[ct], 0, 0, 0);
    }
  }

  // ---- v epilogue: v[c][n] bf16 + per-wave SumV partial into LDS ----
  unsigned short* vbb = vbuf + (size_t)b * CC * NN;
#pragma unroll
  for (int ct = 0; ct < 8; ct++) {
#pragma unroll
    for (int r = 0; r < 4; r++) {
      int c = 16 * ct + 4 * oct + r;
      float val = av[ct][r] + vb[c];
      vbb[(size_t)c * NN + n0 + 16 * w + col] = f2bf(val);
      float sv = val;
      sv += __shfl_xor(sv, 1); sv += __shfl_xor(sv, 2);
      sv += __shfl_xor(sv, 4); sv += __shfl_xor(sv, 8);
      if (col == 0) partV[w][c] = sv;
    }
  }

  // ---- q -> LDS (fp32, biased) ----
#pragma unroll
  for (int ct = 0; ct < 8; ct++) {
#pragma unroll
    for (int r = 0; r < 4; r++) {
      int c = 16 * ct + col;
      qs[w][4 * oct + r][c] = aq[ct][r] + qb[c];
    }
  }
  int row = lane >> 2, cq = (lane & 3) * 32;
  float vals[32];
  float ssq = 0.f;
#pragma unroll
  for (int i = 0; i < 32; i += 4) {
    float4 v4 = *(const float4*)&qs[w][row][cq + i];
    vals[i] = v4.x; vals[i + 1] = v4.y; vals[i + 2] = v4.z; vals[i + 3] = v4.w;
    ssq += v4.x * v4.x + v4.y * v4.y + v4.z * v4.z + v4.w * v4.w;
  }
  ssq += __shfl_xor(ssq, 1); ssq += __shfl_xor(ssq, 2);
  float nm = fmaxf(sqrtf(ssq), 1e-4f), sc = 1.0f / nm;
  int gp = b * NN + n0 + 16 * w + row;
  if ((lane & 3) == 0) nrm[gp] = nm;
  unsigned outq[16], outn[16];
  float sk[32];
#pragma unroll
  for (int i = 0; i < 32; i += 2) {
    unsigned short u0 = f2bf(vals[i]), u1 = f2bf(vals[i + 1]);
    unsigned short m0 = f2bf(vals[i] * sc), m1 = f2bf(vals[i + 1] * sc);
    outq[i >> 1] = (unsigned)u0 | ((unsigned)u1 << 16);
    outn[i >> 1] = (unsigned)m0 | ((unsigned)m1 << 16);
    sk[i] = bf2f((short)m0); sk[i + 1] = bf2f((short)m1);
  }
  unsigned short* qtp = qt + (size_t)gp * CC + cq;
  unsigned short* qnp = qtn + (size_t)gp * CC + cq;
#pragma unroll
  for (int k = 0; k < 4; k++) {
    uint4 v; v.x = outq[4 * k]; v.y = outq[4 * k + 1]; v.z = outq[4 * k + 2]; v.w = outq[4 * k + 3];
    *(uint4*)(qtp + 8 * k) = v;
    uint4 u; u.x = outn[4 * k]; u.y = outn[4 * k + 1]; u.z = outn[4 * k + 2]; u.w = outn[4 * k + 3];
    *(uint4*)(qnp + 8 * k) = u;
  }
#pragma unroll
  for (int i = 0; i < 32; i++) {
    float v = sk[i];
    v += __shfl_xor(v, 4); v += __shfl_xor(v, 8);
    v += __shfl_xor(v, 16); v += __shfl_xor(v, 32);
    if ((lane >> 2) == 0) partK[w][cq + i] = v;
  }

  // ---- heads ----
  f32x4 ah[4];
#pragma unroll
  for (int i = 0; i < 4; i++) ah[i] = (f32x4)0.f;
#pragma unroll
  for (int kc = 0; kc < 4; kc++) {
    float4 a0 = *(const float4*)&qs[w][col][kc * 32 + oct * 8];
    float4 a1 = *(const float4*)&qs[w][col][kc * 32 + oct * 8 + 4];
    union { unsigned short s[8]; bf16x8 v; } af;
    af.s[0] = f2bf(a0.x); af.s[1] = f2bf(a0.y); af.s[2] = f2bf(a0.z); af.s[3] = f2bf(a0.w);
    af.s[4] = f2bf(a1.x); af.s[5] = f2bf(a1.y); af.s[6] = f2bf(a1.z); af.s[7] = f2bf(a1.w);
#pragma unroll
    for (int ct = 0; ct < 4; ct++) {
      bf16x8 Bf = *(const bf16x8*)(hwb + (16 * ct + col) * CC + kc * 32 + oct * 8);
      ah[ct] = __builtin_amdgcn_mfma_f32_16x16x32_bf16(af.v, Bf, ah[ct], 0, 0, 0);
    }
  }
  float b1l[2], b1b[2], w2l[2], w2b[2];
#pragma unroll
  for (int ct = 0; ct < 2; ct++) {
    int mid = 16 * ct + col;
    b1l[ct] = lw1b[mid]; w2l[ct] = lw2w[mid];
    b1b[ct] = bw1b[mid]; w2b[ct] = bw2w[mid];
  }
#pragma unroll
  for (int r = 0; r < 4; r++) {
    float wp = 0.f, bp = 0.f;
#pragma unroll
    for (int ct = 0; ct < 2; ct++) {
      float zl = ah[ct][r] + b1l[ct];
      zl = (zl >= 0.f) ? zl : 0.2f * zl;
      wp += w2l[ct] * zl;
      float zb = ah[ct + 2][r] + b1b[ct];
      zb = (zb >= 0.f) ? zb : 0.2f * zb;
      bp += w2b[ct] * zb;
    }
    wp += __shfl_xor(wp, 1); wp += __shfl_xor(wp, 2);
    wp += __shfl_xor(wp, 4); wp += __shfl_xor(wp, 8);
    bp += __shfl_xor(bp, 1); bp += __shfl_xor(bp, 2);
    bp += __shfl_xor(bp, 4); bp += __shfl_xor(bp, 8);
    if (col == 0) {
      int g = b * NN + n0 + 16 * w + 4 * oct + r;
      wmap[g] = wp + lw2b[0];
      bmap[g] = bp + bw2b[0];
    }
  }

  // ---- block reduction of partials -> coalesced global partial vectors ----
  __syncthreads();
  int blk = b * 64 + nb;
  if (t < 128) {
    float s = (partK[0][t] + partK[1][t]) + (partK[2][t] + partK[3][t]);
    pSkey[(size_t)blk * 128 + t] = s;
  } else {
    int c = t - 128;
    float s = (partV[0][c] + partV[1][c]) + (partV[2][c] + partV[3][c]);
    pSumV[(size_t)blk * 128 + c] = s;
  }
}

// ---------------- reduce: partials -> Skey / SumV ----------------
__global__ __launch_bounds__(256) void reduce_kernel(
    const float* __restrict__ pSkey, const float* __restrict__ pSumV,
    float* __restrict__ Skey, float* __restrict__ SumV) {
  int b = blockIdx.x;
  int t = threadIdx.x;
  const float* src = (t < 128) ? pSkey : pSumV;
  int c = t & 127;
  float s = 0.f;
#pragma unroll 8
  for (int nb = 0; nb < 64; nb++)
    s += src[((size_t)b * 64 + nb) * 128 + c];
  if (t < 128) Skey[b * CC + c] = s;
  else SumV[b * CC + c] = s;
}

// ---------------- qk_sparse: QK^T + Z + bucketed survivor tiles -----------
// grid 1024: lin = mtile*32 + b*8 + ks; block = 128 m x 512 keys (16 iters)
__global__ __launch_bounds__(256, 2) void qk_sparse(
    const unsigned short* __restrict__ qt, const unsigned short* __restrict__ qtn,
    const float* __restrict__ nrm, const float* __restrict__ wmap,
    const float* __restrict__ bmap, const float* __restrict__ Skey,
    float* __restrict__ Zacc, unsigned short* __restrict__ Tb,
    int* __restrict__ blist, int* __restrict__ bcnt,
    int* __restrict__ cnt, int cap) {
  int lin = blockIdx.x;
  int mtile = lin >> 5;
  int bks = lin & 31;
  int b = bks >> 3, ks = bks & 7;
  int t = threadIdx.x, wave = t >> 6, lane = t & 63;
  int col = lane & 15, oct = lane >> 4;
  int m0 = mtile * 128 + 32 * wave;

  __shared__ unsigned short Bt[2][4096];     // frag-major B tiles (8 KB each)
  __shared__ unsigned short tS[4][32][40];   // per-wave survivor transform

  const unsigned short* qtb  = qt  + (size_t)b * NN * CC;
  const unsigned short* qtnb = qtn + (size_t)b * NN * CC;

  bf16x8 A[2][4];
#pragma unroll
  for (int mt = 0; mt < 2; mt++)
#pragma unroll
    for (int kc = 0; kc < 4; kc++)
      A[mt][kc] = *(const bf16x8*)(qtb + (size_t)(m0 + 16 * mt + col) * CC + 32 * kc + 8 * oct);

  // analytic rowsum -> per-row stats c1, zd
  float stc1[2][4], stzd[2][4];
#pragma unroll
  for (int mt = 0; mt < 2; mt++) {
    float dot = 0.f;
#pragma unroll
    for (int kc = 0; kc < 4; kc++) {
      const float* skp = Skey + b * CC + 32 * kc + 8 * oct;
      float4 s0 = *(const float4*)skp;
      float4 s1 = *(const float4*)(skp + 4);
      bf16x8 a = A[mt][kc];
      dot += bf2f(a[0]) * s0.x + bf2f(a[1]) * s0.y + bf2f(a[2]) * s0.z + bf2f(a[3]) * s0.w;
      dot += bf2f(a[4]) * s1.x + bf2f(a[5]) * s1.y + bf2f(a[6]) * s1.z + bf2f(a[7]) * s1.w;
    }
    dot += __shfl_xor(dot, 16);
    dot += __shfl_xor(dot, 32);
    int m = m0 + 16 * mt + col;
    float c1 = dot * (1.0f / NN) * wmap[(size_t)b * NN + m] - bmap[(size_t)b * NN + m];
    float nm = nrm[(size_t)b * NN + m];
    float zd = nm * fmaxf(nm - c1, 0.f);
#pragma unroll
    for (int r = 0; r < 4; r++) {
      stc1[mt][r] = __shfl(c1, 4 * oct + r);
      stzd[mt][r] = __shfl(zd, 4 * oct + r);
    }
  }

  int n0base = ks * 512;
  {
    int f0 = wave, f1 = wave + 4;
    uint4 r0 = *(const uint4*)(qtnb + (size_t)(n0base + 16 * (f0 >> 2) + col) * CC + (4 * (f0 & 3) + oct) * 8);
    uint4 r1 = *(const uint4*)(qtnb + (size_t)(n0base + 16 * (f1 >> 2) + col) * CC + (4 * (f1 & 3) + oct) * 8);
    *(uint4*)&Bt[0][f0 * 512 + lane * 8] = r0;
    *(uint4*)&Bt[0][f1 * 512 + lane * 8] = r1;
  }
  __syncthreads();

  float zp[2][4];
#pragma unroll
  for (int mt = 0; mt < 2; mt++)
#pragma unroll
    for (int r = 0; r < 4; r++) zp[mt][r] = 0.f;
  bool didwork = false;

  for (int it = 0; it < 16; it++) {
    int cur = it & 1;
    bool more = (it + 1 < 16);
    uint4 r0, r1;
    if (more) {
      int n0n = n0base + (it + 1) * 32;
      int f0 = wave, f1 = wave + 4;
      r0 = *(const uint4*)(qtnb + (size_t)(n0n + 16 * (f0 >> 2) + col) * CC + (4 * (f0 & 3) + oct) * 8);
      r1 = *(const uint4*)(qtnb + (size_t)(n0n + 16 * (f1 >> 2) + col) * CC + (4 * (f1 & 3) + oct) * 8);
    }
    f32x4 acc[2][2];
    acc[0][0] = (f32x4)0.f; acc[0][1] = (f32x4)0.f;
    acc[1][0] = (f32x4)0.f; acc[1][1] = (f32x4)0.f;
#pragma unroll
    for (int nt = 0; nt < 2; nt++)
#pragma unroll
      for (int kc = 0; kc < 4; kc++) {
        bf16x8 Bf = *(const bf16x8*)&Bt[cur][(nt * 4 + kc) * 512 + lane * 8];
        acc[0][nt] = __builtin_amdgcn_mfma_f32_16x16x32_bf16(A[0][kc], Bf, acc[0][nt], 0, 0, 0);
        acc[1][nt] = __builtin_amdgcn_mfma_f32_16x16x32_bf16(A[1][kc], Bf, acc[1][nt], 0, 0, 0);
      }
    // cheap row-max screen: max_z_row <= max(lmax*relu(lmax-c1), 0)
    float fm = -1e30f;
#pragma unroll
    for (int mt = 0; mt < 2; mt++)
#pragma unroll
      for (int r = 0; r < 4; r++) {
        float lm = fmaxf(acc[mt][0][r], acc[mt][1][r]);
        float ub = fmaxf(lm * fmaxf(lm - stc1[mt][r], 0.f), 0.f);
        fm = fmaxf(fm, ub - stzd[mt][r]);
      }
    if (__any(fm > -18.4207f)) {
      didwork = true;
      int n0 = n0base + it * 32;
#pragma unroll
      for (int mt = 0; mt < 2; mt++)
#pragma unroll
        for (int nt = 0; nt < 2; nt++)
#pragma unroll
          for (int r = 0; r < 4; r++) {
            float l = acc[mt][nt][r];
            float s = l - stc1[mt][r];
            float z = l * fmaxf(s, 0.f);
            float e = __expf(z - stzd[mt][r]);
            zp[mt][r] += e;
            tS[wave][16 * mt + 4 * oct + r][16 * nt + col] = f2bf((s > 0.f) ? e : 0.f);
          }
      int slot;
      if (lane == 0) {
        slot = atomicAdd(cnt, 1);
        if (slot < cap) {
          int bucket = b * 128 + (m0 >> 5);
          int idx = atomicAdd(&bcnt[bucket], 1);
          if (idx < 128) blist[bucket * 128 + idx] = (slot << 7) | (n0 >> 5);
        }
      }
      slot = __shfl(slot, 0);
      if (slot < cap) {
        const unsigned short* src = &tS[wave][lane >> 1][(lane & 1) * 16];
        unsigned short* dst = Tb + (size_t)slot * 1024 + (lane >> 1) * 32 + (lane & 1) * 16;
        *(uint4*)dst = *(const uint4*)src;
        *(uint4*)(dst + 8) = *(const uint4*)(src + 8);
      }
    }
    if (more) {
      int nxt = cur ^ 1;
      *(uint4*)&Bt[nxt][wave * 512 + lane * 8] = r0;
      *(uint4*)&Bt[nxt][(wave + 4) * 512 + lane * 8] = r1;
    }
    __syncthreads();
  }

  if (didwork) {
#pragma unroll
    for (int mt = 0; mt < 2; mt++)
#pragma unroll
      for (int r = 0; r < 4; r++) {
        float v = zp[mt][r];
        v += __shfl_xor(v, 1); v += __shfl_xor(v, 2);
        v += __shfl_xor(v, 4); v += __shfl_xor(v, 8);
        if (col == 0)
          atomicAdd(Zacc + (size_t)b * NN + m0 + 16 * mt + 4 * oct + r, v);
      }
  }
}

// ---- pv: one block per (b, m0) bucket; 4 tile-groups x 4 channel-waves ----
// 1024 threads; tiles split round-robin over groups; LDS cross-group reduce.
__global__ __launch_bounds__(1024) void pv_kernel(
    const unsigned short* __restrict__ vb16, const unsigned short* __restrict__ Tb,
    const int* __restrict__ blist, const int* __restrict__ bcnt,
    const float* __restrict__ Zacc, const float* __restrict__ SumV,
    unsigned short* __restrict__ Yt) {
  int bucket = blockIdx.x;
  int b = bucket >> 7;
  int m0 = (bucket & 127) * 32;
  int t = threadIdx.x;
  int w = t >> 6, lane = t & 63;
  int grp = w >> 2, cw = w & 3;      // tile group 0..3, channel wave 0..3
  int col = lane & 15, oct = lane >> 4;
  __shared__ int lst[128];
  __shared__ float red[3][32][132];
  int ntiles = bcnt[bucket];
  if (ntiles > 128) ntiles = 128;
  if (t < ntiles) lst[t] = blist[bucket * 128 + t];
  __syncthreads();
  const unsigned short* Vb = vb16 + (size_t)b * CC * NN;

  f32x4 acc[2][2];
  acc[0][0] = (f32x4)0.f; acc[0][1] = (f32x4)0.f;
  acc[1][0] = (f32x4)0.f; acc[1][1] = (f32x4)0.f;

  int nIt = (ntiles > grp) ? ((ntiles - grp + 3) >> 2) : 0;
  bf16x8 Bb[2][2], Ab[2][2];
  auto ldtile = [&](int idx, bf16x8 (&Bf)[2], bf16x8 (&Af)[2]) {
    int e = lst[idx];
    int slot = e >> 7, n0 = (e & 127) * 32;
    const unsigned short* Tp = Tb + (size_t)slot * 1024;
    Bf[0] = *(const bf16x8*)(Tp + col * 32 + 8 * oct);
    Bf[1] = *(const bf16x8*)(Tp + (16 + col) * 32 + 8 * oct);
    Af[0] = *(const bf16x8*)(Vb + (size_t)(32 * cw + col) * NN + n0 + 8 * oct);
    Af[1] = *(const bf16x8*)(Vb + (size_t)(32 * cw + 16 + col) * NN + n0 + 8 * oct);
  };
  if (nIt > 0) ldtile(grp, Bb[0], Ab[0]);
  for (int k = 0; k < nIt; k++) {
    int cur = k & 1, nxt = cur ^ 1;
    if (k + 1 < nIt) ldtile(grp + (k + 1) * 4, Bb[nxt], Ab[nxt]);
#pragma unroll
    for (int ct = 0; ct < 2; ct++)
#pragma unroll
      for (int bt = 0; bt < 2; bt++)
        acc[ct][bt] = __builtin_amdgcn_mfma_f32_16x16x32_bf16(
            Ab[cur][ct], Bb[cur][bt], acc[ct][bt], 0, 0, 0);
  }

  // cross-group reduction: groups 1..3 store, group 0 sums + epilogue
  if (grp > 0) {
#pragma unroll
    for (int bt = 0; bt < 2; bt++)
#pragma unroll
      for (int ct = 0; ct < 2; ct++)
#pragma unroll
        for (int r = 0; r < 4; r++)
          red[grp - 1][16 * bt + col][32 * cw + 16 * ct + 4 * oct + r] = acc[ct][bt][r];
  }
  __syncthreads();
  if (grp == 0) {
#pragma unroll
    for (int bt = 0; bt < 2; bt++) {
      int m = m0 + 16 * bt + col;
      float rZ = 1.0f / Zacc[(size_t)b * NN + m];
      int h = m >> 6, ww = m & 63;
      unsigned short* yp = Yt + ((size_t)b * YTP + (size_t)(h + 1) * 66 + (ww + 1)) * CC + 32 * cw;
#pragma unroll
      for (int ct = 0; ct < 2; ct++) {
        int cbase = 16 * ct + 4 * oct;
        float4 sv = *(const float4*)(SumV + b * CC + 32 * cw + cbase);
        float y[4];
#pragma unroll
        for (int r = 0; r < 4; r++) {
          float a = acc[ct][bt][r]
                  + red[0][16 * bt + col][32 * cw + cbase + r]
                  + red[1][16 * bt + col][32 * cw + cbase + r]
                  + red[2][16 * bt + col][32 * cw + cbase + r];
          y[r] = a * rZ;
        }
        y[0] += 1e-8f * sv.x; y[1] += 1e-8f * sv.y;
        y[2] += 1e-8f * sv.z; y[3] += 1e-8f * sv.w;
        uint2 o;
        o.x = (unsigned)f2bf(y[0]) | ((unsigned)f2bf(y[1]) << 16);
        o.y = (unsigned)f2bf(y[2]) | ((unsigned)f2bf(y[3]) << 16);
        *(uint2*)(yp + cbase) = o;
      }
    }
  }
}

// ---------------- MFMA 3x3 conv + bias + leaky + residual ------------------
__global__ __launch_bounds__(256, 2) void conv_mfma(
    const unsigned short* __restrict__ Yt, const unsigned short* __restrict__ Wt,
    const float* __restrict__ x, const float* __restrict__ lb,
    float* __restrict__ out) {
  int h = blockIdx.x;
  int by = blockIdx.y;
  int b = blockIdx.z;
  int t = threadIdx.x;
  int wave = t >> 6, lane = t & 63;
  int col = lane & 15, oct = lane >> 4;
  int pxt = wave & 1, cohalf = wave >> 1;
  int w0 = by * 32 + pxt * 16;
  const unsigned short* Yb = Yt + (size_t)b * YTP * CC;

  f32x4 acc[4];
#pragma unroll
  for (int ct = 0; ct < 4; ct++) acc[ct] = (f32x4)0.f;

#pragma unroll
  for (int tap = 0; tap < 9; tap++) {
    int dh = tap / 3 - 1, dw = tap % 3 - 1;
    const unsigned short* ybase =
        Yb + (size_t)((h + 1 + dh) * 66 + (w0 + 1 + dw + col)) * CC;
#pragma unroll
    for (int kc = 0; kc < 4; kc++) {
      bf16x8 Af = *(const bf16x8*)(ybase + 32 * kc + 8 * oct);
#pragma unroll
      for (int ct = 0; ct < 4; ct++) {
        bf16x8 Bf = *(const bf16x8*)(Wt +
            (size_t)(cohalf * 64 + 16 * ct + col) * 1152 + tap * 128 + 32 * kc + 8 * oct);
        acc[ct] = __builtin_amdgcn_mfma_f32_16x16x32_bf16(Af, Bf, acc[ct], 0, 0, 0);
      }
    }
  }
#pragma unroll
  for (int ct = 0; ct < 4; ct++) {
    int co = cohalf * 64 + 16 * ct + col;
    float bv = lb[co];
    int n = h * 64 + w0 + 4 * oct;
    size_t base = ((size_t)b * CC + co) * NN + n;
    float4 xi = *(const float4*)(x + base);
    float4 o;
    float z0 = acc[ct][0] + bv; o.x = ((z0 >= 0.f) ? z0 : 0.2f * z0) + xi.x;
    float z1 = acc[ct][1] + bv; o.y = ((z1 >= 0.f) ? z1 : 0.2f * z1) + xi.y;
    float z2 = acc[ct][2] + bv; o.z = ((z2 >= 0.f) ? z2 : 0.2f * z2) + xi.z;
    float z3 = acc[ct][3] + bv; o.w = ((z3 >= 0.f) ? z3 : 0.2f * z3) + xi.w;
    *(float4*)(out + base) = o;
  }
}

extern "C" void kernel_launch(void* const* d_in, const int* in_sizes, int n_in,
                              void* d_out, int out_size, void* d_ws, size_t ws_size,
                              hipStream_t stream) {
  const float* x    = (const float*)d_in[0];
  const float* q_w  = (const float*)d_in[1];
  const float* q_b  = (const float*)d_in[2];
  const float* v_w  = (const float*)d_in[3];
  const float* v_b  = (const float*)d_in[4];
  const float* lw1w = (const float*)d_in[5];
  const float* lw1b = (const float*)d_in[6];
  const float* lw2w = (const float*)d_in[7];
  const float* lw2b = (const float*)d_in[8];
  const float* bw1w = (const float*)d_in[9];
  const float* bw1b = (const float*)d_in[10];
  const float* bw2w = (const float*)d_in[11];
  const float* bw2b = (const float*)d_in[12];
  const float* linw = (const float*)d_in[13];
  const float* linb = (const float*)d_in[14];
  float* out = (float*)d_out;

  const size_t BCN = (size_t)BB * CC * NN;  // 2,097,152
  const size_t BN  = (size_t)BB * NN;       // 16,384

  unsigned short* xtb = (unsigned short*)d_ws;         // BCN bf16
  unsigned short* qt  = xtb + BCN;                     // BCN
  unsigned short* qtn = qt + BCN;                      // BCN
  unsigned short* vb16 = qtn + BCN;                    // BCN
  unsigned short* Yt  = vb16 + BCN;                    // BB*YTP*CC
  unsigned short* qwb = Yt + (size_t)BB * YTP * CC;    // CC*CC
  unsigned short* vwb = qwb + CC * CC;                 // CC*CC
  unsigned short* hwb = vwb + CC * CC;                 // 64*CC
  unsigned short* Wt  = hwb + 64 * CC;                 // CC*1152
  float* nrmb = (float*)(Wt + (size_t)CC * 1152);      // BN
  float* wmap = nrmb + BN;                             // BN
  float* bmap = wmap + BN;                             // BN
  float* SumV = bmap + BN;                             // BB*CC
  float* Skey = SumV + (size_t)BB * CC;                // BB*CC
  float* Zacc = Skey + (size_t)BB * CC;                // BN   } zero
  int*   cnt  = (int*)(Zacc + BN);                     // 16   } region
  int*   bcnt = cnt + 16;                              // 512  }
  float* pSkey = (float*)(bcnt + 512);                 // 256*128
  float* pSumV = pSkey + 256 * 128;                    // 256*128
  int*   blist = (int*)(pSumV + 256 * 128);            // 512*128
  unsigned short* Tb = (unsigned short*)(blist + 512 * 128);

  size_t usedBytes = (size_t)((char*)Tb - (char*)d_ws);
  int cap = 0;
  if (ws_size > usedBytes + 2048)
    cap = (int)((ws_size - usedBytes) / 2048);
  if (cap > METAMAX) cap = METAMAX;

  hipMemsetAsync(Zacc, 0, BN * sizeof(float) + (16 + 512) * sizeof(int), stream);
  hipMemsetAsync(Yt, 0, (size_t)BB * YTP * CC * sizeof(unsigned short), stream);

  hipLaunchKernelGGL(xt_kernel, dim3(NN / 64, BB), dim3(256), 0, stream, x, xtb);
  hipLaunchKernelGGL(wrepack_kernel, dim3((188416 + 255) / 256), dim3(256), 0,
                     stream, q_w, v_w, lw1w, bw1w, linw, qwb, vwb, hwb, Wt);
  hipLaunchKernelGGL(qv_mfma, dim3(NN / 64, BB), dim3(256), 0, stream,
                     xtb, qwb, vwb, hwb, q_b, v_b, lw1b, lw2w, lw2b,
                     bw1b, bw2w, bw2b, qt, qtn, nrmb, pSkey, vb16, pSumV,
                     wmap, bmap);
  hipLaunchKernelGGL(reduce_kernel, dim3(BB), dim3(256), 0, stream,
                     pSkey, pSumV, Skey, SumV);
  hipLaunchKernelGGL(qk_sparse, dim3(1024), dim3(256), 0, stream,
                     qt, qtn, nrmb, wmap, bmap, Skey, Zacc, Tb, blist, bcnt,
                     cnt, cap);
  hipLaunchKernelGGL(pv_kernel, dim3(512), dim3(1024), 0, stream,
                     vb16, Tb, blist, bcnt, Zacc, SumV, Yt);
  hipLaunchKernelGGL(conv_mfma, dim3(HH, 2, BB), dim3(256), 0, stream,
                     Yt, Wt, x, linb, out);
}

// Round 10
// 259.103 us; speedup vs baseline: 7.2953x; 7.2953x over previous
//
#include <hip/hip_runtime.h>
#include <math.h>

#define BB 4
#define CC 128
#define NN 4096
#define HH 64
#define WW 64
#define YTP 4356   // 66*66 padded pixel count
#define METAMAX 65536

typedef __attribute__((ext_vector_type(8))) short bf16x8;
typedef __attribute__((ext_vector_type(4))) float f32x4;

__device__ inline unsigned short f2bf(float f) {
  unsigned int u = __float_as_uint(f);
  unsigned int r = (u + 0x7FFFu + ((u >> 16) & 1u)) >> 16;
  return (unsigned short)r;
}
__device__ inline float bf2f(short s) {
  union { unsigned u; float f; } x;
  x.u = ((unsigned)(unsigned short)s) << 16;
  return x.f;
}

// ---------------- xt: transpose x -> xtb bf16 [b][n][c] ----------------
__global__ __launch_bounds__(256) void xt_kernel(
    const float* __restrict__ x, unsigned short* __restrict__ xtb) {
  int b = blockIdx.y;
  int n0 = blockIdx.x * 64;
  int t = threadIdx.x;
  __shared__ float xs[CC][65];
  for (int l = 0; l < 32; l++) {
    int idx = t + 256 * l;
    int px = idx & 63, c = idx >> 6;
    xs[c][px] = x[((size_t)b * CC + c) * NN + n0 + px];
  }
  __syncthreads();
  int n = t & 63, ch = t >> 6;
  unsigned o[16];
#pragma unroll
  for (int i = 0; i < 32; i += 2) {
    o[i >> 1] = (unsigned)f2bf(xs[32 * ch + i][n]) |
                ((unsigned)f2bf(xs[32 * ch + i + 1][n]) << 16);
  }
  unsigned short* dst = xtb + ((size_t)b * NN + n0 + n) * CC + 32 * ch;
#pragma unroll
  for (int k = 0; k < 4; k++) {
    uint4 v; v.x = o[4 * k]; v.y = o[4 * k + 1]; v.z = o[4 * k + 2]; v.w = o[4 * k + 3];
    *(uint4*)(dst + 8 * k) = v;
  }
}

// ---------------- wrepack: all weights -> bf16 packed ----------------
__global__ __launch_bounds__(256) void wrepack_kernel(
    const float* __restrict__ qw, const float* __restrict__ vw,
    const float* __restrict__ lw1w, const float* __restrict__ bw1w,
    const float* __restrict__ lw, unsigned short* __restrict__ qwb,
    unsigned short* __restrict__ vwb, unsigned short* __restrict__ hwb,
    unsigned short* __restrict__ Wt) {
  int idx = blockIdx.x * 256 + threadIdx.x;
  if (idx < 16384) { qwb[idx] = f2bf(qw[idx]); return; }
  idx -= 16384;
  if (idx < 16384) { vwb[idx] = f2bf(vw[idx]); return; }
  idx -= 16384;
  if (idx < 4096) { hwb[idx] = f2bf(lw1w[idx]); return; }
  idx -= 4096;
  if (idx < 4096) { hwb[4096 + idx] = f2bf(bw1w[idx]); return; }
  idx -= 4096;
  if (idx < CC * 1152) {
    int co = idx / 1152, rem = idx % 1152;
    int tap = rem >> 7, ci = rem & 127;
    Wt[idx] = f2bf(lw[(size_t)(co * CC + ci) * 9 + tap]);
  }
}

// ------- qv_mfma: q[n][c] + v[c][n] + nrm + qt/qtn + partial Skey/SumV + heads
__global__ __launch_bounds__(256) void qv_mfma(
    const unsigned short* __restrict__ xtb, const unsigned short* __restrict__ qwb,
    const unsigned short* __restrict__ vwb, const unsigned short* __restrict__ hwb,
    const float* __restrict__ qb, const float* __restrict__ vb,
    const float* __restrict__ lw1b, const float* __restrict__ lw2w,
    const float* __restrict__ lw2b, const float* __restrict__ bw1b,
    const float* __restrict__ bw2w, const float* __restrict__ bw2b,
    unsigned short* __restrict__ qt, unsigned short* __restrict__ qtn,
    float* __restrict__ nrm, float* __restrict__ pSkey,
    unsigned short* __restrict__ vbuf, float* __restrict__ pSumV,
    float* __restrict__ wmap, float* __restrict__ bmap) {
  int b = blockIdx.y;
  int nb = blockIdx.x;
  int n0 = nb * 64;
  int t = threadIdx.x, w = t >> 6, lane = t & 63;
  int col = lane & 15, oct = lane >> 4;
  __shared__ float qs[4][16][132];
  __shared__ float partK[4][128];
  __shared__ float partV[4][128];
  const unsigned short* xb = xtb + (size_t)b * NN * CC;

  f32x4 aq[8], av[8];
#pragma unroll
  for (int i = 0; i < 8; i++) { aq[i] = (f32x4)0.f; av[i] = (f32x4)0.f; }
#pragma unroll
  for (int kc = 0; kc < 4; kc++) {
    bf16x8 Xf = *(const bf16x8*)(xb + (size_t)(n0 + 16 * w + col) * CC + kc * 32 + oct * 8);
#pragma unroll
    for (int ct = 0; ct < 8; ct++) {
      bf16x8 Qf = *(const bf16x8*)(qwb + (16 * ct + col) * CC + kc * 32 + oct * 8);
      aq[ct] = __builtin_amdgcn_mfma_f32_16x16x32_bf16(Xf, Qf, aq[ct], 0, 0, 0);
      bf16x8 Vf = *(const bf16x8*)(vwb + (16 * ct + col) * CC + kc * 32 + oct * 8);
      av[ct] = __builtin_amdgcn_mfma_f32_16x16x32_bf16(Vf, Xf, av[ct], 0, 0, 0);
    }
  }

  // ---- v epilogue: v[c][n] bf16 + per-wave SumV partial into LDS ----
  unsigned short* vbb = vbuf + (size_t)b * CC * NN;
#pragma unroll
  for (int ct = 0; ct < 8; ct++) {
#pragma unroll
    for (int r = 0; r < 4; r++) {
      int c = 16 * ct + 4 * oct + r;
      float val = av[ct][r] + vb[c];
      vbb[(size_t)c * NN + n0 + 16 * w + col] = f2bf(val);
      float sv = val;
      sv += __shfl_xor(sv, 1); sv += __shfl_xor(sv, 2);
      sv += __shfl_xor(sv, 4); sv += __shfl_xor(sv, 8);
      if (col == 0) partV[w][c] = sv;
    }
  }

  // ---- q -> LDS (fp32, biased) ----
#pragma unroll
  for (int ct = 0; ct < 8; ct++) {
#pragma unroll
    for (int r = 0; r < 4; r++) {
      int c = 16 * ct + col;
      qs[w][4 * oct + r][c] = aq[ct][r] + qb[c];
    }
  }
  int row = lane >> 2, cq = (lane & 3) * 32;
  float vals[32];
  float ssq = 0.f;
#pragma unroll
  for (int i = 0; i < 32; i += 4) {
    float4 v4 = *(const float4*)&qs[w][row][cq + i];
    vals[i] = v4.x; vals[i + 1] = v4.y; vals[i + 2] = v4.z; vals[i + 3] = v4.w;
    ssq += v4.x * v4.x + v4.y * v4.y + v4.z * v4.z + v4.w * v4.w;
  }
  ssq += __shfl_xor(ssq, 1); ssq += __shfl_xor(ssq, 2);
  float nm = fmaxf(sqrtf(ssq), 1e-4f), sc = 1.0f / nm;
  int gp = b * NN + n0 + 16 * w + row;
  if ((lane & 3) == 0) nrm[gp] = nm;
  unsigned outq[16], outn[16];
  float sk[32];
#pragma unroll
  for (int i = 0; i < 32; i += 2) {
    unsigned short u0 = f2bf(vals[i]), u1 = f2bf(vals[i + 1]);
    unsigned short m0 = f2bf(vals[i] * sc), m1 = f2bf(vals[i + 1] * sc);
    outq[i >> 1] = (unsigned)u0 | ((unsigned)u1 << 16);
    outn[i >> 1] = (unsigned)m0 | ((unsigned)m1 << 16);
    sk[i] = bf2f((short)m0); sk[i + 1] = bf2f((short)m1);
  }
  unsigned short* qtp = qt + (size_t)gp * CC + cq;
  unsigned short* qnp = qtn + (size_t)gp * CC + cq;
#pragma unroll
  for (int k = 0; k < 4; k++) {
    uint4 v; v.x = outq[4 * k]; v.y = outq[4 * k + 1]; v.z = outq[4 * k + 2]; v.w = outq[4 * k + 3];
    *(uint4*)(qtp + 8 * k) = v;
    uint4 u; u.x = outn[4 * k]; u.y = outn[4 * k + 1]; u.z = outn[4 * k + 2]; u.w = outn[4 * k + 3];
    *(uint4*)(qnp + 8 * k) = u;
  }
#pragma unroll
  for (int i = 0; i < 32; i++) {
    float v = sk[i];
    v += __shfl_xor(v, 4); v += __shfl_xor(v, 8);
    v += __shfl_xor(v, 16); v += __shfl_xor(v, 32);
    if ((lane >> 2) == 0) partK[w][cq + i] = v;
  }

  // ---- heads ----
  f32x4 ah[4];
#pragma unroll
  for (int i = 0; i < 4; i++) ah[i] = (f32x4)0.f;
#pragma unroll
  for (int kc = 0; kc < 4; kc++) {
    float4 a0 = *(const float4*)&qs[w][col][kc * 32 + oct * 8];
    float4 a1 = *(const float4*)&qs[w][col][kc * 32 + oct * 8 + 4];
    union { unsigned short s[8]; bf16x8 v; } af;
    af.s[0] = f2bf(a0.x); af.s[1] = f2bf(a0.y); af.s[2] = f2bf(a0.z); af.s[3] = f2bf(a0.w);
    af.s[4] = f2bf(a1.x); af.s[5] = f2bf(a1.y); af.s[6] = f2bf(a1.z); af.s[7] = f2bf(a1.w);
#pragma unroll
    for (int ct = 0; ct < 4; ct++) {
      bf16x8 Bf = *(const bf16x8*)(hwb + (16 * ct + col) * CC + kc * 32 + oct * 8);
      ah[ct] = __builtin_amdgcn_mfma_f32_16x16x32_bf16(af.v, Bf, ah[ct], 0, 0, 0);
    }
  }
  float b1l[2], b1b[2], w2l[2], w2b[2];
#pragma unroll
  for (int ct = 0; ct < 2; ct++) {
    int mid = 16 * ct + col;
    b1l[ct] = lw1b[mid]; w2l[ct] = lw2w[mid];
    b1b[ct] = bw1b[mid]; w2b[ct] = bw2w[mid];
  }
#pragma unroll
  for (int r = 0; r < 4; r++) {
    float wp = 0.f, bp = 0.f;
#pragma unroll
    for (int ct = 0; ct < 2; ct++) {
      float zl = ah[ct][r] + b1l[ct];
      zl = (zl >= 0.f) ? zl : 0.2f * zl;
      wp += w2l[ct] * zl;
      float zb = ah[ct + 2][r] + b1b[ct];
      zb = (zb >= 0.f) ? zb : 0.2f * zb;
      bp += w2b[ct] * zb;
    }
    wp += __shfl_xor(wp, 1); wp += __shfl_xor(wp, 2);
    wp += __shfl_xor(wp, 4); wp += __shfl_xor(wp, 8);
    bp += __shfl_xor(bp, 1); bp += __shfl_xor(bp, 2);
    bp += __shfl_xor(bp, 4); bp += __shfl_xor(bp, 8);
    if (col == 0) {
      int g = b * NN + n0 + 16 * w + 4 * oct + r;
      wmap[g] = wp + lw2b[0];
      bmap[g] = bp + bw2b[0];
    }
  }

  // ---- block reduction of partials -> coalesced global partial vectors ----
  __syncthreads();
  int blk = b * 64 + nb;
  if (t < 128) {
    float s = (partK[0][t] + partK[1][t]) + (partK[2][t] + partK[3][t]);
    pSkey[(size_t)blk * 128 + t] = s;
  } else {
    int c = t - 128;
    float s = (partV[0][c] + partV[1][c]) + (partV[2][c] + partV[3][c]);
    pSumV[(size_t)blk * 128 + c] = s;
  }
}

// ---------------- reduce: partials -> Skey / SumV ----------------
__global__ __launch_bounds__(256) void reduce_kernel(
    const float* __restrict__ pSkey, const float* __restrict__ pSumV,
    float* __restrict__ Skey, float* __restrict__ SumV) {
  int b = blockIdx.x;
  int t = threadIdx.x;
  const float* src = (t < 128) ? pSkey : pSumV;
  int c = t & 127;
  float s = 0.f;
#pragma unroll 8
  for (int nb = 0; nb < 64; nb++)
    s += src[((size_t)b * 64 + nb) * 128 + c];
  if (t < 128) Skey[b * CC + c] = s;
  else SumV[b * CC + c] = s;
}

// ---------------- qk_sparse: QK^T + Z + bucketed survivor tiles -----------
// grid 1024: lin = mtile*32 + b*8 + ks; block = 128 m x 512 keys (16 iters)
__global__ __launch_bounds__(256, 2) void qk_sparse(
    const unsigned short* __restrict__ qt, const unsigned short* __restrict__ qtn,
    const float* __restrict__ nrm, const float* __restrict__ wmap,
    const float* __restrict__ bmap, const float* __restrict__ Skey,
    float* __restrict__ Zacc, unsigned short* __restrict__ Tb,
    int* __restrict__ blist, int* __restrict__ bcnt,
    int* __restrict__ cnt, int cap) {
  int lin = blockIdx.x;
  int mtile = lin >> 5;
  int bks = lin & 31;
  int b = bks >> 3, ks = bks & 7;
  int t = threadIdx.x, wave = t >> 6, lane = t & 63;
  int col = lane & 15, oct = lane >> 4;
  int m0 = mtile * 128 + 32 * wave;

  __shared__ unsigned short Bt[2][4096];     // frag-major B tiles (8 KB each)
  __shared__ unsigned short tS[4][32][40];   // per-wave survivor transform

  const unsigned short* qtb  = qt  + (size_t)b * NN * CC;
  const unsigned short* qtnb = qtn + (size_t)b * NN * CC;

  bf16x8 A[2][4];
#pragma unroll
  for (int mt = 0; mt < 2; mt++)
#pragma unroll
    for (int kc = 0; kc < 4; kc++)
      A[mt][kc] = *(const bf16x8*)(qtb + (size_t)(m0 + 16 * mt + col) * CC + 32 * kc + 8 * oct);

  // analytic rowsum -> per-row stats c1, zd
  float stc1[2][4], stzd[2][4];
#pragma unroll
  for (int mt = 0; mt < 2; mt++) {
    float dot = 0.f;
#pragma unroll
    for (int kc = 0; kc < 4; kc++) {
      const float* skp = Skey + b * CC + 32 * kc + 8 * oct;
      float4 s0 = *(const float4*)skp;
      float4 s1 = *(const float4*)(skp + 4);
      bf16x8 a = A[mt][kc];
      dot += bf2f(a[0]) * s0.x + bf2f(a[1]) * s0.y + bf2f(a[2]) * s0.z + bf2f(a[3]) * s0.w;
      dot += bf2f(a[4]) * s1.x + bf2f(a[5]) * s1.y + bf2f(a[6]) * s1.z + bf2f(a[7]) * s1.w;
    }
    dot += __shfl_xor(dot, 16);
    dot += __shfl_xor(dot, 32);
    int m = m0 + 16 * mt + col;
    float c1 = dot * (1.0f / NN) * wmap[(size_t)b * NN + m] - bmap[(size_t)b * NN + m];
    float nm = nrm[(size_t)b * NN + m];
    float zd = nm * fmaxf(nm - c1, 0.f);
#pragma unroll
    for (int r = 0; r < 4; r++) {
      stc1[mt][r] = __shfl(c1, 4 * oct + r);
      stzd[mt][r] = __shfl(zd, 4 * oct + r);
    }
  }

  int n0base = ks * 512;
  {
    int f0 = wave, f1 = wave + 4;
    uint4 r0 = *(const uint4*)(qtnb + (size_t)(n0base + 16 * (f0 >> 2) + col) * CC + (4 * (f0 & 3) + oct) * 8);
    uint4 r1 = *(const uint4*)(qtnb + (size_t)(n0base + 16 * (f1 >> 2) + col) * CC + (4 * (f1 & 3) + oct) * 8);
    *(uint4*)&Bt[0][f0 * 512 + lane * 8] = r0;
    *(uint4*)&Bt[0][f1 * 512 + lane * 8] = r1;
  }
  __syncthreads();

  float zp[2][4];
#pragma unroll
  for (int mt = 0; mt < 2; mt++)
#pragma unroll
    for (int r = 0; r < 4; r++) zp[mt][r] = 0.f;
  bool didwork = false;

  for (int it = 0; it < 16; it++) {
    int cur = it & 1;
    bool more = (it + 1 < 16);
    uint4 r0, r1;
    if (more) {
      int n0n = n0base + (it + 1) * 32;
      int f0 = wave, f1 = wave + 4;
      r0 = *(const uint4*)(qtnb + (size_t)(n0n + 16 * (f0 >> 2) + col) * CC + (4 * (f0 & 3) + oct) * 8);
      r1 = *(const uint4*)(qtnb + (size_t)(n0n + 16 * (f1 >> 2) + col) * CC + (4 * (f1 & 3) + oct) * 8);
    }
    f32x4 acc[2][2];
    acc[0][0] = (f32x4)0.f; acc[0][1] = (f32x4)0.f;
    acc[1][0] = (f32x4)0.f; acc[1][1] = (f32x4)0.f;
#pragma unroll
    for (int nt = 0; nt < 2; nt++)
#pragma unroll
      for (int kc = 0; kc < 4; kc++) {
        bf16x8 Bf = *(const bf16x8*)&Bt[cur][(nt * 4 + kc) * 512 + lane * 8];
        acc[0][nt] = __builtin_amdgcn_mfma_f32_16x16x32_bf16(A[0][kc], Bf, acc[0][nt], 0, 0, 0);
        acc[1][nt] = __builtin_amdgcn_mfma_f32_16x16x32_bf16(A[1][kc], Bf, acc[1][nt], 0, 0, 0);
      }
    // cheap row-max screen: max_z_row <= max(lmax*relu(lmax-c1), 0)
    float fm = -1e30f;
#pragma unroll
    for (int mt = 0; mt < 2; mt++)
#pragma unroll
      for (int r = 0; r < 4; r++) {
        float lm = fmaxf(acc[mt][0][r], acc[mt][1][r]);
        float ub = fmaxf(lm * fmaxf(lm - stc1[mt][r], 0.f), 0.f);
        fm = fmaxf(fm, ub - stzd[mt][r]);
      }
    if (__any(fm > -18.4207f)) {
      didwork = true;
      int n0 = n0base + it * 32;
#pragma unroll
      for (int mt = 0; mt < 2; mt++)
#pragma unroll
        for (int nt = 0; nt < 2; nt++)
#pragma unroll
          for (int r = 0; r < 4; r++) {
            float l = acc[mt][nt][r];
            float s = l - stc1[mt][r];
            float z = l * fmaxf(s, 0.f);
            float e = __expf(z - stzd[mt][r]);
            zp[mt][r] += e;
            tS[wave][16 * mt + 4 * oct + r][16 * nt + col] = f2bf((s > 0.f) ? e : 0.f);
          }
      int slot;
      if (lane == 0) {
        slot = atomicAdd(cnt, 1);
        if (slot < cap) {
          int bucket = b * 128 + (m0 >> 5);
          int idx = atomicAdd(&bcnt[bucket], 1);
          if (idx < 128) blist[bucket * 128 + idx] = (slot << 7) | (n0 >> 5);
        }
      }
      slot = __shfl(slot, 0);
      if (slot < cap) {
        const unsigned short* src = &tS[wave][lane >> 1][(lane & 1) * 16];
        unsigned short* dst = Tb + (size_t)slot * 1024 + (lane >> 1) * 32 + (lane & 1) * 16;
        *(uint4*)dst = *(const uint4*)src;
        *(uint4*)(dst + 8) = *(const uint4*)(src + 8);
      }
    }
    if (more) {
      int nxt = cur ^ 1;
      *(uint4*)&Bt[nxt][wave * 512 + lane * 8] = r0;
      *(uint4*)&Bt[nxt][(wave + 4) * 512 + lane * 8] = r1;
    }
    __syncthreads();
  }

  if (didwork) {
#pragma unroll
    for (int mt = 0; mt < 2; mt++)
#pragma unroll
      for (int r = 0; r < 4; r++) {
        float v = zp[mt][r];
        v += __shfl_xor(v, 1); v += __shfl_xor(v, 2);
        v += __shfl_xor(v, 4); v += __shfl_xor(v, 8);
        if (col == 0)
          atomicAdd(Zacc + (size_t)b * NN + m0 + 16 * mt + 4 * oct + r, v);
      }
  }
}

// ---- pv: one block per (b, m0) bucket; 4 tile-groups x 4 channel-waves ----
// 1024 threads; named ping-pong buffers (NO runtime-indexed register arrays).
__global__ __launch_bounds__(1024) void pv_kernel(
    const unsigned short* __restrict__ vb16, const unsigned short* __restrict__ Tb,
    const int* __restrict__ blist, const int* __restrict__ bcnt,
    const float* __restrict__ Zacc, const float* __restrict__ SumV,
    unsigned short* __restrict__ Yt) {
  int bucket = blockIdx.x;
  int b = bucket >> 7;
  int m0 = (bucket & 127) * 32;
  int t = threadIdx.x;
  int w = t >> 6, lane = t & 63;
  int grp = w >> 2, cw = w & 3;      // tile group 0..3, channel wave 0..3
  int col = lane & 15, oct = lane >> 4;
  __shared__ int lst[128];
  __shared__ float red[3][32][132];
  int ntiles = bcnt[bucket];
  if (ntiles > 128) ntiles = 128;
  if (t < ntiles) lst[t] = blist[bucket * 128 + t];
  __syncthreads();
  const unsigned short* Vb = vb16 + (size_t)b * CC * NN;

  f32x4 acc[2][2];
  acc[0][0] = (f32x4)0.f; acc[0][1] = (f32x4)0.f;
  acc[1][0] = (f32x4)0.f; acc[1][1] = (f32x4)0.f;

  int nIt = (ntiles > grp) ? ((ntiles - grp + 3) >> 2) : 0;
  // named ping-pong buffers: compile-time alternation only
  bf16x8 B0a, B0b, A0a, A0b, B1a, B1b, A1a, A1b;
  auto ld0 = [&](int idx) {
    int e = lst[idx];
    int slot = e >> 7, n0 = (e & 127) * 32;
    const unsigned short* Tp = Tb + (size_t)slot * 1024;
    B0a = *(const bf16x8*)(Tp + col * 32 + 8 * oct);
    B0b = *(const bf16x8*)(Tp + (16 + col) * 32 + 8 * oct);
    A0a = *(const bf16x8*)(Vb + (size_t)(32 * cw + col) * NN + n0 + 8 * oct);
    A0b = *(const bf16x8*)(Vb + (size_t)(32 * cw + 16 + col) * NN + n0 + 8 * oct);
  };
  auto ld1 = [&](int idx) {
    int e = lst[idx];
    int slot = e >> 7, n0 = (e & 127) * 32;
    const unsigned short* Tp = Tb + (size_t)slot * 1024;
    B1a = *(const bf16x8*)(Tp + col * 32 + 8 * oct);
    B1b = *(const bf16x8*)(Tp + (16 + col) * 32 + 8 * oct);
    A1a = *(const bf16x8*)(Vb + (size_t)(32 * cw + col) * NN + n0 + 8 * oct);
    A1b = *(const bf16x8*)(Vb + (size_t)(32 * cw + 16 + col) * NN + n0 + 8 * oct);
  };
  if (nIt > 0) ld0(grp);
  for (int k = 0; k < nIt; k += 2) {
    if (k + 1 < nIt) ld1(grp + (k + 1) * 4);
    acc[0][0] = __builtin_amdgcn_mfma_f32_16x16x32_bf16(A0a, B0a, acc[0][0], 0, 0, 0);
    acc[0][1] = __builtin_amdgcn_mfma_f32_16x16x32_bf16(A0a, B0b, acc[0][1], 0, 0, 0);
    acc[1][0] = __builtin_amdgcn_mfma_f32_16x16x32_bf16(A0b, B0a, acc[1][0], 0, 0, 0);
    acc[1][1] = __builtin_amdgcn_mfma_f32_16x16x32_bf16(A0b, B0b, acc[1][1], 0, 0, 0);
    if (k + 1 < nIt) {
      if (k + 2 < nIt) ld0(grp + (k + 2) * 4);
      acc[0][0] = __builtin_amdgcn_mfma_f32_16x16x32_bf16(A1a, B1a, acc[0][0], 0, 0, 0);
      acc[0][1] = __builtin_amdgcn_mfma_f32_16x16x32_bf16(A1a, B1b, acc[0][1], 0, 0, 0);
      acc[1][0] = __builtin_amdgcn_mfma_f32_16x16x32_bf16(A1b, B1a, acc[1][0], 0, 0, 0);
      acc[1][1] = __builtin_amdgcn_mfma_f32_16x16x32_bf16(A1b, B1b, acc[1][1], 0, 0, 0);
    }
  }

  // cross-group reduction: groups 1..3 store, group 0 sums + epilogue
  if (grp > 0) {
#pragma unroll
    for (int bt = 0; bt < 2; bt++)
#pragma unroll
      for (int ct = 0; ct < 2; ct++)
#pragma unroll
        for (int r = 0; r < 4; r++)
          red[grp - 1][16 * bt + col][32 * cw + 16 * ct + 4 * oct + r] = acc[ct][bt][r];
  }
  __syncthreads();
  if (grp == 0) {
#pragma unroll
    for (int bt = 0; bt < 2; bt++) {
      int m = m0 + 16 * bt + col;
      float rZ = 1.0f / Zacc[(size_t)b * NN + m];
      int h = m >> 6, ww = m & 63;
      unsigned short* yp = Yt + ((size_t)b * YTP + (size_t)(h + 1) * 66 + (ww + 1)) * CC + 32 * cw;
#pragma unroll
      for (int ct = 0; ct < 2; ct++) {
        int cbase = 16 * ct + 4 * oct;
        float4 sv = *(const float4*)(SumV + b * CC + 32 * cw + cbase);
        float y[4];
#pragma unroll
        for (int r = 0; r < 4; r++) {
          float a = acc[ct][bt][r]
                  + red[0][16 * bt + col][32 * cw + cbase + r]
                  + red[1][16 * bt + col][32 * cw + cbase + r]
                  + red[2][16 * bt + col][32 * cw + cbase + r];
          y[r] = a * rZ;
        }
        y[0] += 1e-8f * sv.x; y[1] += 1e-8f * sv.y;
        y[2] += 1e-8f * sv.z; y[3] += 1e-8f * sv.w;
        uint2 o;
        o.x = (unsigned)f2bf(y[0]) | ((unsigned)f2bf(y[1]) << 16);
        o.y = (unsigned)f2bf(y[2]) | ((unsigned)f2bf(y[3]) << 16);
        *(uint2*)(yp + cbase) = o;
      }
    }
  }
}

// ---------------- MFMA 3x3 conv + bias + leaky + residual ------------------
__global__ __launch_bounds__(256, 2) void conv_mfma(
    const unsigned short* __restrict__ Yt, const unsigned short* __restrict__ Wt,
    const float* __restrict__ x, const float* __restrict__ lb,
    float* __restrict__ out) {
  int h = blockIdx.x;
  int by = blockIdx.y;
  int b = blockIdx.z;
  int t = threadIdx.x;
  int wave = t >> 6, lane = t & 63;
  int col = lane & 15, oct = lane >> 4;
  int pxt = wave & 1, cohalf = wave >> 1;
  int w0 = by * 32 + pxt * 16;
  const unsigned short* Yb = Yt + (size_t)b * YTP * CC;

  f32x4 acc[4];
#pragma unroll
  for (int ct = 0; ct < 4; ct++) acc[ct] = (f32x4)0.f;

#pragma unroll
  for (int tap = 0; tap < 9; tap++) {
    int dh = tap / 3 - 1, dw = tap % 3 - 1;
    const unsigned short* ybase =
        Yb + (size_t)((h + 1 + dh) * 66 + (w0 + 1 + dw + col)) * CC;
#pragma unroll
    for (int kc = 0; kc < 4; kc++) {
      bf16x8 Af = *(const bf16x8*)(ybase + 32 * kc + 8 * oct);
#pragma unroll
      for (int ct = 0; ct < 4; ct++) {
        bf16x8 Bf = *(const bf16x8*)(Wt +
            (size_t)(cohalf * 64 + 16 * ct + col) * 1152 + tap * 128 + 32 * kc + 8 * oct);
        acc[ct] = __builtin_amdgcn_mfma_f32_16x16x32_bf16(Af, Bf, acc[ct], 0, 0, 0);
      }
    }
  }
#pragma unroll
  for (int ct = 0; ct < 4; ct++) {
    int co = cohalf * 64 + 16 * ct + col;
    float bv = lb[co];
    int n = h * 64 + w0 + 4 * oct;
    size_t base = ((size_t)b * CC + co) * NN + n;
    float4 xi = *(const float4*)(x + base);
    float4 o;
    float z0 = acc[ct][0] + bv; o.x = ((z0 >= 0.f) ? z0 : 0.2f * z0) + xi.x;
    float z1 = acc[ct][1] + bv; o.y = ((z1 >= 0.f) ? z1 : 0.2f * z1) + xi.y;
    float z2 = acc[ct][2] + bv; o.z = ((z2 >= 0.f) ? z2 : 0.2f * z2) + xi.z;
    float z3 = acc[ct][3] + bv; o.w = ((z3 >= 0.f) ? z3 : 0.2f * z3) + xi.w;
    *(float4*)(out + base) = o;
  }
}

extern "C" void kernel_launch(void* const* d_in, const int* in_sizes, int n_in,
                              void* d_out, int out_size, void* d_ws, size_t ws_size,
                              hipStream_t stream) {
  const float* x    = (const float*)d_in[0];
  const float* q_w  = (const float*)d_in[1];
  const float* q_b  = (const float*)d_in[2];
  const float* v_w  = (const float*)d_in[3];
  const float* v_b  = (const float*)d_in[4];
  const float* lw1w = (const float*)d_in[5];
  const float* lw1b = (const float*)d_in[6];
  const float* lw2w = (const float*)d_in[7];
  const float* lw2b = (const float*)d_in[8];
  const float* bw1w = (const float*)d_in[9];
  const float* bw1b = (const float*)d_in[10];
  const float* bw2w = (const float*)d_in[11];
  const float* bw2b = (const float*)d_in[12];
  const float* linw = (const float*)d_in[13];
  const float* linb = (const float*)d_in[14];
  float* out = (float*)d_out;

  const size_t BCN = (size_t)BB * CC * NN;  // 2,097,152
  const size_t BN  = (size_t)BB * NN;       // 16,384

  unsigned short* xtb = (unsigned short*)d_ws;         // BCN bf16
  unsigned short* qt  = xtb + BCN;                     // BCN
  unsigned short* qtn = qt + BCN;                      // BCN
  unsigned short* vb16 = qtn + BCN;                    // BCN
  unsigned short* Yt  = vb16 + BCN;                    // BB*YTP*CC
  unsigned short* qwb = Yt + (size_t)BB * YTP * CC;    // CC*CC
  unsigned short* vwb = qwb + CC * CC;                 // CC*CC
  unsigned short* hwb = vwb + CC * CC;                 // 64*CC
  unsigned short* Wt  = hwb + 64 * CC;                 // CC*1152
  float* nrmb = (float*)(Wt + (size_t)CC * 1152);      // BN
  float* wmap = nrmb + BN;                             // BN
  float* bmap = wmap + BN;                             // BN
  float* SumV = bmap + BN;                             // BB*CC
  float* Skey = SumV + (size_t)BB * CC;                // BB*CC
  float* Zacc = Skey + (size_t)BB * CC;                // BN   } zero
  int*   cnt  = (int*)(Zacc + BN);                     // 16   } region
  int*   bcnt = cnt + 16;                              // 512  }
  float* pSkey = (float*)(bcnt + 512);                 // 256*128
  float* pSumV = pSkey + 256 * 128;                    // 256*128
  int*   blist = (int*)(pSumV + 256 * 128);            // 512*128
  unsigned short* Tb = (unsigned short*)(blist + 512 * 128);

  size_t usedBytes = (size_t)((char*)Tb - (char*)d_ws);
  int cap = 0;
  if (ws_size > usedBytes + 2048)
    cap = (int)((ws_size - usedBytes) / 2048);
  if (cap > METAMAX) cap = METAMAX;

  hipMemsetAsync(Zacc, 0, BN * sizeof(float) + (16 + 512) * sizeof(int), stream);
  hipMemsetAsync(Yt, 0, (size_t)BB * YTP * CC * sizeof(unsigned short), stream);

  hipLaunchKernelGGL(xt_kernel, dim3(NN / 64, BB), dim3(256), 0, stream, x, xtb);
  hipLaunchKernelGGL(wrepack_kernel, dim3((188416 + 255) / 256), dim3(256), 0,
                     stream, q_w, v_w, lw1w, bw1w, linw, qwb, vwb, hwb, Wt);
  hipLaunchKernelGGL(qv_mfma, dim3(NN / 64, BB), dim3(256), 0, stream,
                     xtb, qwb, vwb, hwb, q_b, v_b, lw1b, lw2w, lw2b,
                     bw1b, bw2w, bw2b, qt, qtn, nrmb, pSkey, vb16, pSumV,
                     wmap, bmap);
  hipLaunchKernelGGL(reduce_kernel, dim3(BB), dim3(256), 0, stream,
                     pSkey, pSumV, Skey, SumV);
  hipLaunchKernelGGL(qk_sparse, dim3(1024), dim3(256), 0, stream,
                     qt, qtn, nrmb, wmap, bmap, Skey, Zacc, Tb, blist, bcnt,
                     cnt, cap);
  hipLaunchKernelGGL(pv_kernel, dim3(512), dim3(1024), 0, stream,
                     vb16, Tb, blist, bcnt, Zacc, SumV, Yt);
  hipLaunchKernelGGL(conv_mfma, dim3(HH, 2, BB), dim3(256), 0, stream,
                     Yt, Wt, x, linb, out);
}

// Round 11
// 258.614 us; speedup vs baseline: 7.3091x; 1.0019x over previous
//
#include <hip/hip_runtime.h>
#include <math.h>

#define BB 4
#define CC 128
#define NN 4096
#define HH 64
#define WW 64
#define YTP 4356   // 66*66 padded pixel count
#define METAMAX 65536

typedef __attribute__((ext_vector_type(8))) short bf16x8;
typedef __attribute__((ext_vector_type(4))) float f32x4;

__device__ inline unsigned short f2bf(float f) {
  unsigned int u = __float_as_uint(f);
  unsigned int r = (u + 0x7FFFu + ((u >> 16) & 1u)) >> 16;
  return (unsigned short)r;
}
__device__ inline float bf2f(short s) {
  union { unsigned u; float f; } x;
  x.u = ((unsigned)(unsigned short)s) << 16;
  return x.f;
}

// ---------------- xt: transpose x -> xtb bf16 [b][n][c] ----------------
__global__ __launch_bounds__(256) void xt_kernel(
    const float* __restrict__ x, unsigned short* __restrict__ xtb) {
  int b = blockIdx.y;
  int n0 = blockIdx.x * 64;
  int t = threadIdx.x;
  __shared__ float xs[CC][65];
  for (int l = 0; l < 32; l++) {
    int idx = t + 256 * l;
    int px = idx & 63, c = idx >> 6;
    xs[c][px] = x[((size_t)b * CC + c) * NN + n0 + px];
  }
  __syncthreads();
  int n = t & 63, ch = t >> 6;
  unsigned o[16];
#pragma unroll
  for (int i = 0; i < 32; i += 2) {
    o[i >> 1] = (unsigned)f2bf(xs[32 * ch + i][n]) |
                ((unsigned)f2bf(xs[32 * ch + i + 1][n]) << 16);
  }
  unsigned short* dst = xtb + ((size_t)b * NN + n0 + n) * CC + 32 * ch;
#pragma unroll
  for (int k = 0; k < 4; k++) {
    uint4 v; v.x = o[4 * k]; v.y = o[4 * k + 1]; v.z = o[4 * k + 2]; v.w = o[4 * k + 3];
    *(uint4*)(dst + 8 * k) = v;
  }
}

// ---------------- wrepack: all weights -> bf16 packed ----------------
__global__ __launch_bounds__(256) void wrepack_kernel(
    const float* __restrict__ qw, const float* __restrict__ vw,
    const float* __restrict__ lw1w, const float* __restrict__ bw1w,
    const float* __restrict__ lw, unsigned short* __restrict__ qwb,
    unsigned short* __restrict__ vwb, unsigned short* __restrict__ hwb,
    unsigned short* __restrict__ Wt) {
  int idx = blockIdx.x * 256 + threadIdx.x;
  if (idx < 16384) { qwb[idx] = f2bf(qw[idx]); return; }
  idx -= 16384;
  if (idx < 16384) { vwb[idx] = f2bf(vw[idx]); return; }
  idx -= 16384;
  if (idx < 4096) { hwb[idx] = f2bf(lw1w[idx]); return; }
  idx -= 4096;
  if (idx < 4096) { hwb[4096 + idx] = f2bf(bw1w[idx]); return; }
  idx -= 4096;
  if (idx < CC * 1152) {
    int co = idx / 1152, rem = idx % 1152;
    int tap = rem >> 7, ci = rem & 127;
    Wt[idx] = f2bf(lw[(size_t)(co * CC + ci) * 9 + tap]);
  }
}

// ------- qv_mfma: q[n][c] + v[c][n] + nrm + qt/qtn + partial Skey/SumV + heads
__global__ __launch_bounds__(256) void qv_mfma(
    const unsigned short* __restrict__ xtb, const unsigned short* __restrict__ qwb,
    const unsigned short* __restrict__ vwb, const unsigned short* __restrict__ hwb,
    const float* __restrict__ qb, const float* __restrict__ vb,
    const float* __restrict__ lw1b, const float* __restrict__ lw2w,
    const float* __restrict__ lw2b, const float* __restrict__ bw1b,
    const float* __restrict__ bw2w, const float* __restrict__ bw2b,
    unsigned short* __restrict__ qt, unsigned short* __restrict__ qtn,
    float* __restrict__ nrm, float* __restrict__ pSkey,
    unsigned short* __restrict__ vbuf, float* __restrict__ pSumV,
    float* __restrict__ wmap, float* __restrict__ bmap) {
  int b = blockIdx.y;
  int nb = blockIdx.x;
  int n0 = nb * 64;
  int t = threadIdx.x, w = t >> 6, lane = t & 63;
  int col = lane & 15, oct = lane >> 4;
  __shared__ float qs[4][16][132];
  __shared__ float partK[4][128];
  __shared__ float partV[4][128];
  const unsigned short* xb = xtb + (size_t)b * NN * CC;

  f32x4 aq[8], av[8];
#pragma unroll
  for (int i = 0; i < 8; i++) { aq[i] = (f32x4)0.f; av[i] = (f32x4)0.f; }
#pragma unroll
  for (int kc = 0; kc < 4; kc++) {
    bf16x8 Xf = *(const bf16x8*)(xb + (size_t)(n0 + 16 * w + col) * CC + kc * 32 + oct * 8);
#pragma unroll
    for (int ct = 0; ct < 8; ct++) {
      bf16x8 Qf = *(const bf16x8*)(qwb + (16 * ct + col) * CC + kc * 32 + oct * 8);
      aq[ct] = __builtin_amdgcn_mfma_f32_16x16x32_bf16(Xf, Qf, aq[ct], 0, 0, 0);
      bf16x8 Vf = *(const bf16x8*)(vwb + (16 * ct + col) * CC + kc * 32 + oct * 8);
      av[ct] = __builtin_amdgcn_mfma_f32_16x16x32_bf16(Vf, Xf, av[ct], 0, 0, 0);
    }
  }

  // ---- v epilogue: v[c][n] bf16 + per-wave SumV partial into LDS ----
  unsigned short* vbb = vbuf + (size_t)b * CC * NN;
#pragma unroll
  for (int ct = 0; ct < 8; ct++) {
#pragma unroll
    for (int r = 0; r < 4; r++) {
      int c = 16 * ct + 4 * oct + r;
      float val = av[ct][r] + vb[c];
      vbb[(size_t)c * NN + n0 + 16 * w + col] = f2bf(val);
      float sv = val;
      sv += __shfl_xor(sv, 1); sv += __shfl_xor(sv, 2);
      sv += __shfl_xor(sv, 4); sv += __shfl_xor(sv, 8);
      if (col == 0) partV[w][c] = sv;
    }
  }

  // ---- q -> LDS (fp32, biased) ----
#pragma unroll
  for (int ct = 0; ct < 8; ct++) {
#pragma unroll
    for (int r = 0; r < 4; r++) {
      int c = 16 * ct + col;
      qs[w][4 * oct + r][c] = aq[ct][r] + qb[c];
    }
  }
  int row = lane >> 2, cq = (lane & 3) * 32;
  float vals[32];
  float ssq = 0.f;
#pragma unroll
  for (int i = 0; i < 32; i += 4) {
    float4 v4 = *(const float4*)&qs[w][row][cq + i];
    vals[i] = v4.x; vals[i + 1] = v4.y; vals[i + 2] = v4.z; vals[i + 3] = v4.w;
    ssq += v4.x * v4.x + v4.y * v4.y + v4.z * v4.z + v4.w * v4.w;
  }
  ssq += __shfl_xor(ssq, 1); ssq += __shfl_xor(ssq, 2);
  float nm = fmaxf(sqrtf(ssq), 1e-4f), sc = 1.0f / nm;
  int gp = b * NN + n0 + 16 * w + row;
  if ((lane & 3) == 0) nrm[gp] = nm;
  unsigned outq[16], outn[16];
  float sk[32];
#pragma unroll
  for (int i = 0; i < 32; i += 2) {
    unsigned short u0 = f2bf(vals[i]), u1 = f2bf(vals[i + 1]);
    unsigned short m0 = f2bf(vals[i] * sc), m1 = f2bf(vals[i + 1] * sc);
    outq[i >> 1] = (unsigned)u0 | ((unsigned)u1 << 16);
    outn[i >> 1] = (unsigned)m0 | ((unsigned)m1 << 16);
    sk[i] = bf2f((short)m0); sk[i + 1] = bf2f((short)m1);
  }
  unsigned short* qtp = qt + (size_t)gp * CC + cq;
  unsigned short* qnp = qtn + (size_t)gp * CC + cq;
#pragma unroll
  for (int k = 0; k < 4; k++) {
    uint4 v; v.x = outq[4 * k]; v.y = outq[4 * k + 1]; v.z = outq[4 * k + 2]; v.w = outq[4 * k + 3];
    *(uint4*)(qtp + 8 * k) = v;
    uint4 u; u.x = outn[4 * k]; u.y = outn[4 * k + 1]; u.z = outn[4 * k + 2]; u.w = outn[4 * k + 3];
    *(uint4*)(qnp + 8 * k) = u;
  }
#pragma unroll
  for (int i = 0; i < 32; i++) {
    float v = sk[i];
    v += __shfl_xor(v, 4); v += __shfl_xor(v, 8);
    v += __shfl_xor(v, 16); v += __shfl_xor(v, 32);
    if ((lane >> 2) == 0) partK[w][cq + i] = v;
  }

  // ---- heads ----
  f32x4 ah[4];
#pragma unroll
  for (int i = 0; i < 4; i++) ah[i] = (f32x4)0.f;
#pragma unroll
  for (int kc = 0; kc < 4; kc++) {
    float4 a0 = *(const float4*)&qs[w][col][kc * 32 + oct * 8];
    float4 a1 = *(const float4*)&qs[w][col][kc * 32 + oct * 8 + 4];
    union { unsigned short s[8]; bf16x8 v; } af;
    af.s[0] = f2bf(a0.x); af.s[1] = f2bf(a0.y); af.s[2] = f2bf(a0.z); af.s[3] = f2bf(a0.w);
    af.s[4] = f2bf(a1.x); af.s[5] = f2bf(a1.y); af.s[6] = f2bf(a1.z); af.s[7] = f2bf(a1.w);
#pragma unroll
    for (int ct = 0; ct < 4; ct++) {
      bf16x8 Bf = *(const bf16x8*)(hwb + (16 * ct + col) * CC + kc * 32 + oct * 8);
      ah[ct] = __builtin_amdgcn_mfma_f32_16x16x32_bf16(af.v, Bf, ah[ct], 0, 0, 0);
    }
  }
  float b1l[2], b1b[2], w2l[2], w2b[2];
#pragma unroll
  for (int ct = 0; ct < 2; ct++) {
    int mid = 16 * ct + col;
    b1l[ct] = lw1b[mid]; w2l[ct] = lw2w[mid];
    b1b[ct] = bw1b[mid]; w2b[ct] = bw2w[mid];
  }
#pragma unroll
  for (int r = 0; r < 4; r++) {
    float wp = 0.f, bp = 0.f;
#pragma unroll
    for (int ct = 0; ct < 2; ct++) {
      float zl = ah[ct][r] + b1l[ct];
      zl = (zl >= 0.f) ? zl : 0.2f * zl;
      wp += w2l[ct] * zl;
      float zb = ah[ct + 2][r] + b1b[ct];
      zb = (zb >= 0.f) ? zb : 0.2f * zb;
      bp += w2b[ct] * zb;
    }
    wp += __shfl_xor(wp, 1); wp += __shfl_xor(wp, 2);
    wp += __shfl_xor(wp, 4); wp += __shfl_xor(wp, 8);
    bp += __shfl_xor(bp, 1); bp += __shfl_xor(bp, 2);
    bp += __shfl_xor(bp, 4); bp += __shfl_xor(bp, 8);
    if (col == 0) {
      int g = b * NN + n0 + 16 * w + 4 * oct + r;
      wmap[g] = wp + lw2b[0];
      bmap[g] = bp + bw2b[0];
    }
  }

  // ---- block reduction of partials -> coalesced global partial vectors ----
  __syncthreads();
  int blk = b * 64 + nb;
  if (t < 128) {
    float s = (partK[0][t] + partK[1][t]) + (partK[2][t] + partK[3][t]);
    pSkey[(size_t)blk * 128 + t] = s;
  } else {
    int c = t - 128;
    float s = (partV[0][c] + partV[1][c]) + (partV[2][c] + partV[3][c]);
    pSumV[(size_t)blk * 128 + c] = s;
  }
}

// ---------------- reduce: partials -> Skey / SumV ----------------
__global__ __launch_bounds__(256) void reduce_kernel(
    const float* __restrict__ pSkey, const float* __restrict__ pSumV,
    float* __restrict__ Skey, float* __restrict__ SumV) {
  int b = blockIdx.x;
  int t = threadIdx.x;
  const float* src = (t < 128) ? pSkey : pSumV;
  int c = t & 127;
  float s = 0.f;
#pragma unroll 8
  for (int nb = 0; nb < 64; nb++)
    s += src[((size_t)b * 64 + nb) * 128 + c];
  if (t < 128) Skey[b * CC + c] = s;
  else SumV[b * CC + c] = s;
}

// ---------------- qk_sparse: QK^T + Z + bucketed survivor tiles -----------
// grid 1024: lin = mtile*32 + b*8 + ks; block = 128 m x 512 keys (16 iters)
__global__ __launch_bounds__(256, 2) void qk_sparse(
    const unsigned short* __restrict__ qt, const unsigned short* __restrict__ qtn,
    const float* __restrict__ nrm, const float* __restrict__ wmap,
    const float* __restrict__ bmap, const float* __restrict__ Skey,
    float* __restrict__ Zacc, unsigned short* __restrict__ Tb,
    int* __restrict__ blist, int* __restrict__ bcnt,
    int* __restrict__ cnt, int cap) {
  int lin = blockIdx.x;
  int mtile = lin >> 5;
  int bks = lin & 31;
  int b = bks >> 3, ks = bks & 7;
  int t = threadIdx.x, wave = t >> 6, lane = t & 63;
  int col = lane & 15, oct = lane >> 4;
  int m0 = mtile * 128 + 32 * wave;

  __shared__ unsigned short Bt[2][4096];     // frag-major B tiles (8 KB each)
  __shared__ unsigned short tS[4][32][40];   // per-wave survivor transform

  const unsigned short* qtb  = qt  + (size_t)b * NN * CC;
  const unsigned short* qtnb = qtn + (size_t)b * NN * CC;

  bf16x8 A[2][4];
#pragma unroll
  for (int mt = 0; mt < 2; mt++)
#pragma unroll
    for (int kc = 0; kc < 4; kc++)
      A[mt][kc] = *(const bf16x8*)(qtb + (size_t)(m0 + 16 * mt + col) * CC + 32 * kc + 8 * oct);

  // analytic rowsum -> per-row stats c1, zd
  float stc1[2][4], stzd[2][4];
#pragma unroll
  for (int mt = 0; mt < 2; mt++) {
    float dot = 0.f;
#pragma unroll
    for (int kc = 0; kc < 4; kc++) {
      const float* skp = Skey + b * CC + 32 * kc + 8 * oct;
      float4 s0 = *(const float4*)skp;
      float4 s1 = *(const float4*)(skp + 4);
      bf16x8 a = A[mt][kc];
      dot += bf2f(a[0]) * s0.x + bf2f(a[1]) * s0.y + bf2f(a[2]) * s0.z + bf2f(a[3]) * s0.w;
      dot += bf2f(a[4]) * s1.x + bf2f(a[5]) * s1.y + bf2f(a[6]) * s1.z + bf2f(a[7]) * s1.w;
    }
    dot += __shfl_xor(dot, 16);
    dot += __shfl_xor(dot, 32);
    int m = m0 + 16 * mt + col;
    float c1 = dot * (1.0f / NN) * wmap[(size_t)b * NN + m] - bmap[(size_t)b * NN + m];
    float nm = nrm[(size_t)b * NN + m];
    float zd = nm * fmaxf(nm - c1, 0.f);
#pragma unroll
    for (int r = 0; r < 4; r++) {
      stc1[mt][r] = __shfl(c1, 4 * oct + r);
      stzd[mt][r] = __shfl(zd, 4 * oct + r);
    }
  }

  int n0base = ks * 512;
  {
    int f0 = wave, f1 = wave + 4;
    uint4 r0 = *(const uint4*)(qtnb + (size_t)(n0base + 16 * (f0 >> 2) + col) * CC + (4 * (f0 & 3) + oct) * 8);
    uint4 r1 = *(const uint4*)(qtnb + (size_t)(n0base + 16 * (f1 >> 2) + col) * CC + (4 * (f1 & 3) + oct) * 8);
    *(uint4*)&Bt[0][f0 * 512 + lane * 8] = r0;
    *(uint4*)&Bt[0][f1 * 512 + lane * 8] = r1;
  }
  __syncthreads();

  float zp[2][4];
#pragma unroll
  for (int mt = 0; mt < 2; mt++)
#pragma unroll
    for (int r = 0; r < 4; r++) zp[mt][r] = 0.f;
  bool didwork = false;

  for (int it = 0; it < 16; it++) {
    int cur = it & 1;
    bool more = (it + 1 < 16);
    uint4 r0, r1;
    if (more) {
      int n0n = n0base + (it + 1) * 32;
      int f0 = wave, f1 = wave + 4;
      r0 = *(const uint4*)(qtnb + (size_t)(n0n + 16 * (f0 >> 2) + col) * CC + (4 * (f0 & 3) + oct) * 8);
      r1 = *(const uint4*)(qtnb + (size_t)(n0n + 16 * (f1 >> 2) + col) * CC + (4 * (f1 & 3) + oct) * 8);
    }
    f32x4 acc[2][2];
    acc[0][0] = (f32x4)0.f; acc[0][1] = (f32x4)0.f;
    acc[1][0] = (f32x4)0.f; acc[1][1] = (f32x4)0.f;
#pragma unroll
    for (int nt = 0; nt < 2; nt++)
#pragma unroll
      for (int kc = 0; kc < 4; kc++) {
        bf16x8 Bf = *(const bf16x8*)&Bt[cur][(nt * 4 + kc) * 512 + lane * 8];
        acc[0][nt] = __builtin_amdgcn_mfma_f32_16x16x32_bf16(A[0][kc], Bf, acc[0][nt], 0, 0, 0);
        acc[1][nt] = __builtin_amdgcn_mfma_f32_16x16x32_bf16(A[1][kc], Bf, acc[1][nt], 0, 0, 0);
      }
    // cheap row-max screen: max_z_row <= max(lmax*relu(lmax-c1), 0)
    float fm = -1e30f;
#pragma unroll
    for (int mt = 0; mt < 2; mt++)
#pragma unroll
      for (int r = 0; r < 4; r++) {
        float lm = fmaxf(acc[mt][0][r], acc[mt][1][r]);
        float ub = fmaxf(lm * fmaxf(lm - stc1[mt][r], 0.f), 0.f);
        fm = fmaxf(fm, ub - stzd[mt][r]);
      }
    if (__any(fm > -18.4207f)) {
      didwork = true;
      int n0 = n0base + it * 32;
#pragma unroll
      for (int mt = 0; mt < 2; mt++)
#pragma unroll
        for (int nt = 0; nt < 2; nt++)
#pragma unroll
          for (int r = 0; r < 4; r++) {
            float l = acc[mt][nt][r];
            float s = l - stc1[mt][r];
            float z = l * fmaxf(s, 0.f);
            float e = __expf(z - stzd[mt][r]);
            zp[mt][r] += e;
            tS[wave][16 * mt + 4 * oct + r][16 * nt + col] = f2bf((s > 0.f) ? e : 0.f);
          }
      int slot;
      if (lane == 0) {
        slot = atomicAdd(cnt, 1);
        if (slot < cap) {
          int bucket = b * 128 + (m0 >> 5);
          int idx = atomicAdd(&bcnt[bucket], 1);
          if (idx < 128) blist[bucket * 128 + idx] = (slot << 7) | (n0 >> 5);
        }
      }
      slot = __shfl(slot, 0);
      if (slot < cap) {
        const unsigned short* src = &tS[wave][lane >> 1][(lane & 1) * 16];
        unsigned short* dst = Tb + (size_t)slot * 1024 + (lane >> 1) * 32 + (lane & 1) * 16;
        *(uint4*)dst = *(const uint4*)src;
        *(uint4*)(dst + 8) = *(const uint4*)(src + 8);
      }
    }
    if (more) {
      int nxt = cur ^ 1;
      *(uint4*)&Bt[nxt][wave * 512 + lane * 8] = r0;
      *(uint4*)&Bt[nxt][(wave + 4) * 512 + lane * 8] = r1;
    }
    __syncthreads();
  }

  if (didwork) {
#pragma unroll
    for (int mt = 0; mt < 2; mt++)
#pragma unroll
      for (int r = 0; r < 4; r++) {
        float v = zp[mt][r];
        v += __shfl_xor(v, 1); v += __shfl_xor(v, 2);
        v += __shfl_xor(v, 4); v += __shfl_xor(v, 8);
        if (col == 0)
          atomicAdd(Zacc + (size_t)b * NN + m0 + 16 * mt + 4 * oct + r, v);
      }
  }
}

// ---- pv: one block per (b, m0) bucket; 4 tile-groups x 4 channel-waves ----
// 1024 threads; named ping-pong buffers; launch_bounds(1024,1) so the
// allocator keeps all 8 fragment buffers live (VGPR 32 -> serialized loads
// was the round-10 bottleneck: 3420 cyc/iter = 4x900 HBM loads in a chain).
__global__ __launch_bounds__(1024, 1) void pv_kernel(
    const unsigned short* __restrict__ vb16, const unsigned short* __restrict__ Tb,
    const int* __restrict__ blist, const int* __restrict__ bcnt,
    const float* __restrict__ Zacc, const float* __restrict__ SumV,
    unsigned short* __restrict__ Yt) {
  int bucket = blockIdx.x;
  int b = bucket >> 7;
  int m0 = (bucket & 127) * 32;
  int t = threadIdx.x;
  int w = t >> 6, lane = t & 63;
  int grp = w >> 2, cw = w & 3;      // tile group 0..3, channel wave 0..3
  int col = lane & 15, oct = lane >> 4;
  __shared__ int lst[128];
  __shared__ float red[3][32][132];
  int ntiles = bcnt[bucket];
  if (ntiles > 128) ntiles = 128;
  if (t < ntiles) lst[t] = blist[bucket * 128 + t];
  __syncthreads();
  const unsigned short* Vb = vb16 + (size_t)b * CC * NN;

  f32x4 acc[2][2];
  acc[0][0] = (f32x4)0.f; acc[0][1] = (f32x4)0.f;
  acc[1][0] = (f32x4)0.f; acc[1][1] = (f32x4)0.f;

  int nIt = (ntiles > grp) ? ((ntiles - grp + 3) >> 2) : 0;
  // named ping-pong buffers: compile-time alternation only
  bf16x8 B0a, B0b, A0a, A0b, B1a, B1b, A1a, A1b;
  auto ld0 = [&](int idx) {
    int e = lst[idx];
    int slot = e >> 7, n0 = (e & 127) * 32;
    const unsigned short* Tp = Tb + (size_t)slot * 1024;
    B0a = *(const bf16x8*)(Tp + col * 32 + 8 * oct);
    B0b = *(const bf16x8*)(Tp + (16 + col) * 32 + 8 * oct);
    A0a = *(const bf16x8*)(Vb + (size_t)(32 * cw + col) * NN + n0 + 8 * oct);
    A0b = *(const bf16x8*)(Vb + (size_t)(32 * cw + 16 + col) * NN + n0 + 8 * oct);
  };
  auto ld1 = [&](int idx) {
    int e = lst[idx];
    int slot = e >> 7, n0 = (e & 127) * 32;
    const unsigned short* Tp = Tb + (size_t)slot * 1024;
    B1a = *(const bf16x8*)(Tp + col * 32 + 8 * oct);
    B1b = *(const bf16x8*)(Tp + (16 + col) * 32 + 8 * oct);
    A1a = *(const bf16x8*)(Vb + (size_t)(32 * cw + col) * NN + n0 + 8 * oct);
    A1b = *(const bf16x8*)(Vb + (size_t)(32 * cw + 16 + col) * NN + n0 + 8 * oct);
  };
  if (nIt > 0) ld0(grp);
  for (int k = 0; k < nIt; k += 2) {
    if (k + 1 < nIt) ld1(grp + (k + 1) * 4);
    acc[0][0] = __builtin_amdgcn_mfma_f32_16x16x32_bf16(A0a, B0a, acc[0][0], 0, 0, 0);
    acc[0][1] = __builtin_amdgcn_mfma_f32_16x16x32_bf16(A0a, B0b, acc[0][1], 0, 0, 0);
    acc[1][0] = __builtin_amdgcn_mfma_f32_16x16x32_bf16(A0b, B0a, acc[1][0], 0, 0, 0);
    acc[1][1] = __builtin_amdgcn_mfma_f32_16x16x32_bf16(A0b, B0b, acc[1][1], 0, 0, 0);
    if (k + 1 < nIt) {
      if (k + 2 < nIt) ld0(grp + (k + 2) * 4);
      acc[0][0] = __builtin_amdgcn_mfma_f32_16x16x32_bf16(A1a, B1a, acc[0][0], 0, 0, 0);
      acc[0][1] = __builtin_amdgcn_mfma_f32_16x16x32_bf16(A1a, B1b, acc[0][1], 0, 0, 0);
      acc[1][0] = __builtin_amdgcn_mfma_f32_16x16x32_bf16(A1b, B1a, acc[1][0], 0, 0, 0);
      acc[1][1] = __builtin_amdgcn_mfma_f32_16x16x32_bf16(A1b, B1b, acc[1][1], 0, 0, 0);
    }
  }

  // cross-group reduction: groups 1..3 store, group 0 sums + epilogue
  if (grp > 0) {
#pragma unroll
    for (int bt = 0; bt < 2; bt++)
#pragma unroll
      for (int ct = 0; ct < 2; ct++)
#pragma unroll
        for (int r = 0; r < 4; r++)
          red[grp - 1][16 * bt + col][32 * cw + 16 * ct + 4 * oct + r] = acc[ct][bt][r];
  }
  __syncthreads();
  if (grp == 0) {
#pragma unroll
    for (int bt = 0; bt < 2; bt++) {
      int m = m0 + 16 * bt + col;
      float rZ = 1.0f / Zacc[(size_t)b * NN + m];
      int h = m >> 6, ww = m & 63;
      unsigned short* yp = Yt + ((size_t)b * YTP + (size_t)(h + 1) * 66 + (ww + 1)) * CC + 32 * cw;
#pragma unroll
      for (int ct = 0; ct < 2; ct++) {
        int cbase = 16 * ct + 4 * oct;
        float4 sv = *(const float4*)(SumV + b * CC + 32 * cw + cbase);
        float y[4];
#pragma unroll
        for (int r = 0; r < 4; r++) {
          float a = acc[ct][bt][r]
                  + red[0][16 * bt + col][32 * cw + cbase + r]
                  + red[1][16 * bt + col][32 * cw + cbase + r]
                  + red[2][16 * bt + col][32 * cw + cbase + r];
          y[r] = a * rZ;
        }
        y[0] += 1e-8f * sv.x; y[1] += 1e-8f * sv.y;
        y[2] += 1e-8f * sv.z; y[3] += 1e-8f * sv.w;
        uint2 o;
        o.x = (unsigned)f2bf(y[0]) | ((unsigned)f2bf(y[1]) << 16);
        o.y = (unsigned)f2bf(y[2]) | ((unsigned)f2bf(y[3]) << 16);
        *(uint2*)(yp + cbase) = o;
      }
    }
  }
}

// ---------------- MFMA 3x3 conv + bias + leaky + residual ------------------
__global__ __launch_bounds__(256, 2) void conv_mfma(
    const unsigned short* __restrict__ Yt, const unsigned short* __restrict__ Wt,
    const float* __restrict__ x, const float* __restrict__ lb,
    float* __restrict__ out) {
  int h = blockIdx.x;
  int by = blockIdx.y;
  int b = blockIdx.z;
  int t = threadIdx.x;
  int wave = t >> 6, lane = t & 63;
  int col = lane & 15, oct = lane >> 4;
  int pxt = wave & 1, cohalf = wave >> 1;
  int w0 = by * 32 + pxt * 16;
  const unsigned short* Yb = Yt + (size_t)b * YTP * CC;

  f32x4 acc[4];
#pragma unroll
  for (int ct = 0; ct < 4; ct++) acc[ct] = (f32x4)0.f;

#pragma unroll
  for (int tap = 0; tap < 9; tap++) {
    int dh = tap / 3 - 1, dw = tap % 3 - 1;
    const unsigned short* ybase =
        Yb + (size_t)((h + 1 + dh) * 66 + (w0 + 1 + dw + col)) * CC;
#pragma unroll
    for (int kc = 0; kc < 4; kc++) {
      bf16x8 Af = *(const bf16x8*)(ybase + 32 * kc + 8 * oct);
#pragma unroll
      for (int ct = 0; ct < 4; ct++) {
        bf16x8 Bf = *(const bf16x8*)(Wt +
            (size_t)(cohalf * 64 + 16 * ct + col) * 1152 + tap * 128 + 32 * kc + 8 * oct);
        acc[ct] = __builtin_amdgcn_mfma_f32_16x16x32_bf16(Af, Bf, acc[ct], 0, 0, 0);
      }
    }
  }
#pragma unroll
  for (int ct = 0; ct < 4; ct++) {
    int co = cohalf * 64 + 16 * ct + col;
    float bv = lb[co];
    int n = h * 64 + w0 + 4 * oct;
    size_t base = ((size_t)b * CC + co) * NN + n;
    float4 xi = *(const float4*)(x + base);
    float4 o;
    float z0 = acc[ct][0] + bv; o.x = ((z0 >= 0.f) ? z0 : 0.2f * z0) + xi.x;
    float z1 = acc[ct][1] + bv; o.y = ((z1 >= 0.f) ? z1 : 0.2f * z1) + xi.y;
    float z2 = acc[ct][2] + bv; o.z = ((z2 >= 0.f) ? z2 : 0.2f * z2) + xi.z;
    float z3 = acc[ct][3] + bv; o.w = ((z3 >= 0.f) ? z3 : 0.2f * z3) + xi.w;
    *(float4*)(out + base) = o;
  }
}

extern "C" void kernel_launch(void* const* d_in, const int* in_sizes, int n_in,
                              void* d_out, int out_size, void* d_ws, size_t ws_size,
                              hipStream_t stream) {
  const float* x    = (const float*)d_in[0];
  const float* q_w  = (const float*)d_in[1];
  const float* q_b  = (const float*)d_in[2];
  const float* v_w  = (const float*)d_in[3];
  const float* v_b  = (const float*)d_in[4];
  const float* lw1w = (const float*)d_in[5];
  const float* lw1b = (const float*)d_in[6];
  const float* lw2w = (const float*)d_in[7];
  const float* lw2b = (const float*)d_in[8];
  const float* bw1w = (const float*)d_in[9];
  const float* bw1b = (const float*)d_in[10];
  const float* bw2w = (const float*)d_in[11];
  const float* bw2b = (const float*)d_in[12];
  const float* linw = (const float*)d_in[13];
  const float* linb = (const float*)d_in[14];
  float* out = (float*)d_out;

  const size_t BCN = (size_t)BB * CC * NN;  // 2,097,152
  const size_t BN  = (size_t)BB * NN;       // 16,384

  unsigned short* xtb = (unsigned short*)d_ws;         // BCN bf16
  unsigned short* qt  = xtb + BCN;                     // BCN
  unsigned short* qtn = qt + BCN;                      // BCN
  unsigned short* vb16 = qtn + BCN;                    // BCN
  unsigned short* Yt  = vb16 + BCN;                    // BB*YTP*CC
  unsigned short* qwb = Yt + (size_t)BB * YTP * CC;    // CC*CC
  unsigned short* vwb = qwb + CC * CC;                 // CC*CC
  unsigned short* hwb = vwb + CC * CC;                 // 64*CC
  unsigned short* Wt  = hwb + 64 * CC;                 // CC*1152
  float* nrmb = (float*)(Wt + (size_t)CC * 1152);      // BN
  float* wmap = nrmb + BN;                             // BN
  float* bmap = wmap + BN;                             // BN
  float* SumV = bmap + BN;                             // BB*CC
  float* Skey = SumV + (size_t)BB * CC;                // BB*CC
  float* Zacc = Skey + (size_t)BB * CC;                // BN   } zero
  int*   cnt  = (int*)(Zacc + BN);                     // 16   } region
  int*   bcnt = cnt + 16;                              // 512  }
  float* pSkey = (float*)(bcnt + 512);                 // 256*128
  float* pSumV = pSkey + 256 * 128;                    // 256*128
  int*   blist = (int*)(pSumV + 256 * 128);            // 512*128
  unsigned short* Tb = (unsigned short*)(blist + 512 * 128);

  size_t usedBytes = (size_t)((char*)Tb - (char*)d_ws);
  int cap = 0;
  if (ws_size > usedBytes + 2048)
    cap = (int)((ws_size - usedBytes) / 2048);
  if (cap > METAMAX) cap = METAMAX;

  hipMemsetAsync(Zacc, 0, BN * sizeof(float) + (16 + 512) * sizeof(int), stream);
  hipMemsetAsync(Yt, 0, (size_t)BB * YTP * CC * sizeof(unsigned short), stream);

  hipLaunchKernelGGL(xt_kernel, dim3(NN / 64, BB), dim3(256), 0, stream, x, xtb);
  hipLaunchKernelGGL(wrepack_kernel, dim3((188416 + 255) / 256), dim3(256), 0,
                     stream, q_w, v_w, lw1w, bw1w, linw, qwb, vwb, hwb, Wt);
  hipLaunchKernelGGL(qv_mfma, dim3(NN / 64, BB), dim3(256), 0, stream,
                     xtb, qwb, vwb, hwb, q_b, v_b, lw1b, lw2w, lw2b,
                     bw1b, bw2w, bw2b, qt, qtn, nrmb, pSkey, vb16, pSumV,
                     wmap, bmap);
  hipLaunchKernelGGL(reduce_kernel, dim3(BB), dim3(256), 0, stream,
                     pSkey, pSumV, Skey, SumV);
  hipLaunchKernelGGL(qk_sparse, dim3(1024), dim3(256), 0, stream,
                     qt, qtn, nrmb, wmap, bmap, Skey, Zacc, Tb, blist, bcnt,
                     cnt, cap);
  hipLaunchKernelGGL(pv_kernel, dim3(512), dim3(1024), 0, stream,
                     vb16, Tb, blist, bcnt, Zacc, SumV, Yt);
  hipLaunchKernelGGL(conv_mfma, dim3(HH, 2, BB), dim3(256), 0, stream,
                     Yt, Wt, x, linb, out);
}